// Round 9
// baseline (3168.399 us; speedup 1.0000x reference)
//
#include <hip/hip_runtime.h>
#include <cstddef>

// ---------------------------------------------------------------------------
// RQ-VAE forward on MI355X. Round 22: e2 -> conv_oct_k (NPY=4, OCT=8,
// 3 blocks/CU) and convt_k launch_bounds (256,2)->(256,3).
// R21 post-mortem: conv3_k was neutral -- corrected model shows the 3x3s
// were already near their 2-wave/SIMD VALU floor (broadcast ds_read_b128 is
// cheaper than the spread-address 12cyc figure). Remaining sick layers:
// e2 (8 FMA/read, 64 reads/thread/ic) and convt occupancy. e2's historical
// NPY=4 regression (R12) was the 2-blocks/CU cliff at OCT=16; OCT=8 keeps
// acc+patch ~125 VGPR -> fits (256,3) = 12 waves/CU with grid 1024.
// Accumulation order per output unchanged everywhere -> bit-exact.
// rvq_k (R18), conv3_k (R21), conv1x1_k, e1 conv_k unchanged.
// ---------------------------------------------------------------------------

template<int ACT> __device__ __forceinline__ float actf(float v) {
    if constexpr (ACT == 1) return v > 0.f ? v : 0.f;            // relu
    else if constexpr (ACT == 2) return v > 0.f ? v : 0.01f * v; // leaky relu
    else return v;
}
__device__ __forceinline__ float lrelu_in(float v) { return v > 0.f ? v : 0.01f * v; }

// ---------------------------------------------------------------------------
// Direct conv (e1): thread = NPY rows x 16 oc. (validated R8)
// ---------------------------------------------------------------------------
template<int CIN, int COUT, int K, int S, int P, int HIN, int WIN, int HOUT, int WOUT,
         int ICC, int NPY, int ACT, bool BIAS>
__launch_bounds__(256, (NPY >= 4 ? 2 : 4))
__global__ void conv_k(const float* __restrict__ in, const float* __restrict__ w,
                       const float* __restrict__ bias, float* __restrict__ out)
{
    constexpr int K2 = K * K;
    constexpr int NR = S * (NPY - 1) + K;
    constexpr int BH = 16 * NPY;
    __shared__ float sw[ICC * K2 * 16];
    const int tid = threadIdx.x;
    const int tx = tid & 15, ty = tid >> 4;
    constexpr int TW = WOUT / 16;
    const int bx = blockIdx.x % TW, by = blockIdx.x / TW;
    const int ox = bx * 16 + tx;
    const int oy0 = by * BH + ty * NPY;
    const int oc0 = blockIdx.y * 16;
    const int n = blockIdx.z;
    const int ix0 = ox * S - P, iy0 = oy0 * S - P;

    int ro[NR]; float mr[NR];
#pragma unroll
    for (int r = 0; r < NR; ++r) {
        const int iy = iy0 + r;
        const bool v = (iy >= 0) && (iy < HIN);
        ro[r] = v ? iy * WIN : 0;
        mr[r] = v ? 1.f : 0.f;
    }
    int co[K]; float mc[K];
#pragma unroll
    for (int c = 0; c < K; ++c) {
        const int ix = ix0 + c;
        const bool v = (ix >= 0) && (ix < WIN);
        co[c] = v ? ix : 0;
        mc[c] = v ? 1.f : 0.f;
    }

    float acc[NPY][16];
#pragma unroll
    for (int py = 0; py < NPY; ++py)
#pragma unroll
        for (int j = 0; j < 16; ++j) acc[py][j] = 0.f;

    for (int ic0 = 0; ic0 < CIN; ic0 += ICC) {
        __syncthreads();
        for (int t = tid; t < ICC * K2 * 16; t += 256) {
            int oc_l = t & 15, r = t >> 4, k = r % K2, ic_l = r / K2;
            sw[(ic_l * K2 + k) * 16 + oc_l] =
                w[((size_t)(oc0 + oc_l) * CIN + ic0 + ic_l) * K2 + k];
        }
        __syncthreads();
#pragma unroll 1
        for (int ic_l = 0; ic_l < ICC; ++ic_l) {
            const float* ip = in + (size_t)(n * CIN + ic0 + ic_l) * HIN * WIN;
            float patch[NR][K];
#pragma unroll
            for (int r = 0; r < NR; ++r)
#pragma unroll
                for (int c = 0; c < K; ++c)
                    patch[r][c] = ip[ro[r] + co[c]] * (mr[r] * mc[c]);
            const float* swp = &sw[ic_l * K2 * 16];
#pragma unroll
            for (int ky = 0; ky < K; ++ky) {
#pragma unroll
                for (int kx = 0; kx < K; ++kx) {
                    const float4* wp = (const float4*)&swp[(ky * K + kx) * 16];
                    float4 w0 = wp[0], w1 = wp[1], w2 = wp[2], w3 = wp[3];
#pragma unroll
                    for (int py = 0; py < NPY; ++py) {
                        const float v = patch[py * S + ky][kx];
                        acc[py][0]  = fmaf(w0.x, v, acc[py][0]);
                        acc[py][1]  = fmaf(w0.y, v, acc[py][1]);
                        acc[py][2]  = fmaf(w0.z, v, acc[py][2]);
                        acc[py][3]  = fmaf(w0.w, v, acc[py][3]);
                        acc[py][4]  = fmaf(w1.x, v, acc[py][4]);
                        acc[py][5]  = fmaf(w1.y, v, acc[py][5]);
                        acc[py][6]  = fmaf(w1.z, v, acc[py][6]);
                        acc[py][7]  = fmaf(w1.w, v, acc[py][7]);
                        acc[py][8]  = fmaf(w2.x, v, acc[py][8]);
                        acc[py][9]  = fmaf(w2.y, v, acc[py][9]);
                        acc[py][10] = fmaf(w2.z, v, acc[py][10]);
                        acc[py][11] = fmaf(w2.w, v, acc[py][11]);
                        acc[py][12] = fmaf(w3.x, v, acc[py][12]);
                        acc[py][13] = fmaf(w3.y, v, acc[py][13]);
                        acc[py][14] = fmaf(w3.z, v, acc[py][14]);
                        acc[py][15] = fmaf(w3.w, v, acc[py][15]);
                    }
                }
            }
        }
    }
#pragma unroll
    for (int py = 0; py < NPY; ++py) {
#pragma unroll
        for (int j = 0; j < 16; ++j) {
            float r = acc[py][j];
            if (BIAS) r += bias[oc0 + j];
            r = actf<ACT>(r);
            out[((size_t)(n * COUT + oc0 + j) * HOUT + oy0 + py) * WOUT + ox] = r;
        }
    }
}

// ---------------------------------------------------------------------------
// conv_oct_k (R22, for e2): thread = NPY rows x OCT oc; OCT=8 keeps
// 16 FMA/ds_read with acc+patch small enough for launch_bounds(256,3)
// (12 waves/CU -- fixes the R12 2-blocks/CU cliff that OCT=16 NPY=4 hit).
// Accumulation order per output (ic chunked by ICC -> ky -> kx) identical
// to conv_k -> bit-exact.
// ---------------------------------------------------------------------------
template<int CIN, int COUT, int K, int S, int P, int HIN, int WIN, int HOUT, int WOUT,
         int ICC, int NPY, int OCT, int MINW, int ACT, bool BIAS>
__launch_bounds__(256, MINW)
__global__ void conv_oct_k(const float* __restrict__ in, const float* __restrict__ w,
                           const float* __restrict__ bias, float* __restrict__ out)
{
    constexpr int K2 = K * K;
    constexpr int NR = S * (NPY - 1) + K;
    constexpr int BH = 16 * NPY;
    __shared__ float sw[ICC * K2 * OCT];
    const int tid = threadIdx.x;
    const int tx = tid & 15, ty = tid >> 4;
    constexpr int TW = WOUT / 16;
    const int bx = blockIdx.x % TW, by = blockIdx.x / TW;
    const int ox = bx * 16 + tx;
    const int oy0 = by * BH + ty * NPY;
    const int oc0 = blockIdx.y * OCT;
    const int n = blockIdx.z;
    const int ix0 = ox * S - P, iy0 = oy0 * S - P;

    int ro[NR]; float mr[NR];
#pragma unroll
    for (int r = 0; r < NR; ++r) {
        const int iy = iy0 + r;
        const bool v = (iy >= 0) && (iy < HIN);
        ro[r] = v ? iy * WIN : 0;
        mr[r] = v ? 1.f : 0.f;
    }
    int co[K]; float mc[K];
#pragma unroll
    for (int c = 0; c < K; ++c) {
        const int ix = ix0 + c;
        const bool v = (ix >= 0) && (ix < WIN);
        co[c] = v ? ix : 0;
        mc[c] = v ? 1.f : 0.f;
    }

    float acc[NPY][OCT];
#pragma unroll
    for (int py = 0; py < NPY; ++py)
#pragma unroll
        for (int j = 0; j < OCT; ++j) acc[py][j] = 0.f;

    for (int ic0 = 0; ic0 < CIN; ic0 += ICC) {
        __syncthreads();
        for (int t = tid; t < ICC * K2 * OCT; t += 256) {
            int oc_l = t % OCT, r = t / OCT, k = r % K2, ic_l = r / K2;
            sw[(ic_l * K2 + k) * OCT + oc_l] =
                w[((size_t)(oc0 + oc_l) * CIN + ic0 + ic_l) * K2 + k];
        }
        __syncthreads();
#pragma unroll 1
        for (int ic_l = 0; ic_l < ICC; ++ic_l) {
            const float* ip = in + (size_t)(n * CIN + ic0 + ic_l) * HIN * WIN;
            float patch[NR][K];
#pragma unroll
            for (int r = 0; r < NR; ++r)
#pragma unroll
                for (int c = 0; c < K; ++c)
                    patch[r][c] = ip[ro[r] + co[c]] * (mr[r] * mc[c]);
            const float* swp = &sw[ic_l * K2 * OCT];
#pragma unroll
            for (int ky = 0; ky < K; ++ky) {
#pragma unroll
                for (int kx = 0; kx < K; ++kx) {
                    const float4* wp = (const float4*)&swp[(ky * K + kx) * OCT];
#pragma unroll
                    for (int q4 = 0; q4 < OCT / 4; ++q4) {
                        const float4 wv = wp[q4];
#pragma unroll
                        for (int py = 0; py < NPY; ++py) {
                            const float v = patch[py * S + ky][kx];
                            acc[py][q4 * 4 + 0] = fmaf(wv.x, v, acc[py][q4 * 4 + 0]);
                            acc[py][q4 * 4 + 1] = fmaf(wv.y, v, acc[py][q4 * 4 + 1]);
                            acc[py][q4 * 4 + 2] = fmaf(wv.z, v, acc[py][q4 * 4 + 2]);
                            acc[py][q4 * 4 + 3] = fmaf(wv.w, v, acc[py][q4 * 4 + 3]);
                        }
                    }
                }
            }
        }
    }
#pragma unroll
    for (int py = 0; py < NPY; ++py) {
#pragma unroll
        for (int j = 0; j < OCT; ++j) {
            float r = acc[py][j];
            if (BIAS) r += bias[oc0 + j];
            r = actf<ACT>(r);
            out[((size_t)(n * COUT + oc0 + j) * HOUT + oy0 + py) * WOUT + ox] = r;
        }
    }
}

// ---------------------------------------------------------------------------
// conv3_k: 3x3 s1 p1 on 64x64 maps, OCT=8 oc x NPY=8 rows per thread.
// (validated R21; near its 2-wave/SIMD VALU floor)
// ---------------------------------------------------------------------------
template<int CIN, int COUT, int ICC, int ACT, bool BIAS>
__launch_bounds__(256, 2)
__global__ void conv3_k(const float* __restrict__ in, const float* __restrict__ w,
                        const float* __restrict__ bias, float* __restrict__ out)
{
    constexpr int HW = 64;
    __shared__ float sw[ICC * 9 * 8];
    const int tid = threadIdx.x;
    const int tx = tid & 31, ty = tid >> 5;     // 32 x 8
    const int ox = blockIdx.x * 32 + tx;
    const int oy0 = ty * 8;
    const int oc0 = blockIdx.y * 8;
    const int n = blockIdx.z;

    int ro[10]; float mr[10];
#pragma unroll
    for (int r = 0; r < 10; ++r) {
        const int iy = oy0 - 1 + r;
        const bool v = (iy >= 0) && (iy < HW);
        ro[r] = v ? iy * HW : 0;
        mr[r] = v ? 1.f : 0.f;
    }
    int co[3]; float mc[3];
#pragma unroll
    for (int c = 0; c < 3; ++c) {
        const int ix = ox - 1 + c;
        const bool v = (ix >= 0) && (ix < HW);
        co[c] = v ? ix : 0;
        mc[c] = v ? 1.f : 0.f;
    }

    float acc[8][8];
#pragma unroll
    for (int py = 0; py < 8; ++py)
#pragma unroll
        for (int j = 0; j < 8; ++j) acc[py][j] = 0.f;

    for (int ic0 = 0; ic0 < CIN; ic0 += ICC) {
        __syncthreads();
        for (int t = tid; t < ICC * 9 * 8; t += 256) {
            int oc_l = t & 7, r = t >> 3, k = r % 9, ic_l = r / 9;
            sw[(ic_l * 9 + k) * 8 + oc_l] =
                w[((size_t)(oc0 + oc_l) * CIN + ic0 + ic_l) * 9 + k];
        }
        __syncthreads();
#pragma unroll 1
        for (int ic_l = 0; ic_l < ICC; ++ic_l) {
            const float* ip = in + (size_t)(n * CIN + ic0 + ic_l) * HW * HW;
            float patch[10][3];
#pragma unroll
            for (int r = 0; r < 10; ++r)
#pragma unroll
                for (int c = 0; c < 3; ++c)
                    patch[r][c] = ip[ro[r] + co[c]] * (mr[r] * mc[c]);
            const float* swp = &sw[ic_l * 9 * 8];
#pragma unroll
            for (int ky = 0; ky < 3; ++ky) {
#pragma unroll
                for (int kx = 0; kx < 3; ++kx) {
                    const float4* wp = (const float4*)&swp[(ky * 3 + kx) * 8];
                    float4 w0 = wp[0], w1 = wp[1];
#pragma unroll
                    for (int py = 0; py < 8; ++py) {
                        const float v = patch[py + ky][kx];
                        acc[py][0] = fmaf(w0.x, v, acc[py][0]);
                        acc[py][1] = fmaf(w0.y, v, acc[py][1]);
                        acc[py][2] = fmaf(w0.z, v, acc[py][2]);
                        acc[py][3] = fmaf(w0.w, v, acc[py][3]);
                        acc[py][4] = fmaf(w1.x, v, acc[py][4]);
                        acc[py][5] = fmaf(w1.y, v, acc[py][5]);
                        acc[py][6] = fmaf(w1.z, v, acc[py][6]);
                        acc[py][7] = fmaf(w1.w, v, acc[py][7]);
                    }
                }
            }
        }
    }
#pragma unroll
    for (int py = 0; py < 8; ++py) {
#pragma unroll
        for (int j = 0; j < 8; ++j) {
            float r = acc[py][j];
            if (BIAS) r += bias[oc0 + j];
            r = actf<ACT>(r);
            out[((size_t)(n * COUT + oc0 + j) * HW + oy0 + py) * HW + ox] = r;
        }
    }
}

// ---------------------------------------------------------------------------
// 1x1 conv over 64x64 maps (HW=4096), NPX pixels per thread. (validated R8)
// ---------------------------------------------------------------------------
template<int CIN, int COUT, int NPX, int ACT, bool BIAS, bool INL, bool RESID, bool TOK>
__launch_bounds__(256, 3)
__global__ void conv1x1_k(const float* __restrict__ in, const float* __restrict__ w,
                          const float* __restrict__ bias, const float* __restrict__ resid,
                          float* __restrict__ out)
{
    constexpr int HW = 4096;
    __shared__ float sw[16 * CIN];
    const int tid = threadIdx.x;
    const int base = blockIdx.x * (256 * NPX) + tid;
    const int oc0 = blockIdx.y * 16;
    const int n = blockIdx.z;

    for (int t = tid; t < 16 * CIN; t += 256) {
        int oc_l = t & 15, ic = t >> 4;
        sw[ic * 16 + oc_l] = w[(size_t)(oc0 + oc_l) * CIN + ic];
    }
    __syncthreads();

    float acc[NPX][16];
#pragma unroll
    for (int p = 0; p < NPX; ++p)
#pragma unroll
        for (int j = 0; j < 16; ++j) acc[p][j] = 0.f;

    const float* ip = in + (size_t)n * CIN * HW;
#pragma unroll 2
    for (int ic = 0; ic < CIN; ++ic) {
        float v[NPX];
#pragma unroll
        for (int p = 0; p < NPX; ++p) {
            float t = ip[(size_t)ic * HW + base + 256 * p];
            if (INL) t = lrelu_in(t);
            v[p] = t;
        }
        const float4* wp = (const float4*)&sw[ic * 16];
#pragma unroll
        for (int q4 = 0; q4 < 4; ++q4) {
            const float4 wv = wp[q4];
#pragma unroll
            for (int p = 0; p < NPX; ++p) {
                acc[p][q4 * 4 + 0] = fmaf(wv.x, v[p], acc[p][q4 * 4 + 0]);
                acc[p][q4 * 4 + 1] = fmaf(wv.y, v[p], acc[p][q4 * 4 + 1]);
                acc[p][q4 * 4 + 2] = fmaf(wv.z, v[p], acc[p][q4 * 4 + 2]);
                acc[p][q4 * 4 + 3] = fmaf(wv.w, v[p], acc[p][q4 * 4 + 3]);
            }
        }
    }
#pragma unroll
    for (int p = 0; p < NPX; ++p) {
        const int pix = base + 256 * p;
#pragma unroll
        for (int j = 0; j < 16; ++j) {
            float r = acc[p][j];
            if (BIAS) r += bias[oc0 + j];
            r = actf<ACT>(r);
            if (RESID) r += resid[((size_t)(n * COUT + oc0 + j)) * HW + pix];
            if (TOK)
                out[((size_t)n * HW + pix) * COUT + oc0 + j] = r;
            else
                out[((size_t)(n * COUT + oc0 + j)) * HW + pix] = r;
        }
    }
}

// ---------------------------------------------------------------------------
// ConvTranspose2d k=4 s=2 p=1, parity decomposition, 2 A-rows per thread,
// OCT small so acc fits (validated R20). R22: launch_bounds (256,2)->(256,3)
// for 3 blocks/CU on the 1024-block grids (VGPR ~100-120 fits the 170 cap).
// ---------------------------------------------------------------------------
template<int CIN, int COUT, int OCT, int HIN, int ICC, int ACT, bool INL>
__launch_bounds__(256, 3)
__global__ void convt_k(const float* __restrict__ in, const float* __restrict__ w,
                        const float* __restrict__ bias, float* __restrict__ out)
{
    constexpr int WIN = HIN, HOUT = 2 * HIN, WOUT = 2 * HIN;
    __shared__ float sw[ICC * 16 * OCT];
    const int tid = threadIdx.x;
    const int tx = tid & 15, ty = tid >> 4;
    constexpr int TBW = WOUT / 32;
    const int bx = blockIdx.x % TBW, by = blockIdx.x / TBW;
    const int A0 = by * 32 + ty;
    const int A1 = A0 + 16;
    const int C = bx * 16 + tx;
    const int oc0 = blockIdx.y * OCT;
    const int n = blockIdx.z;

    int offs[2][9]; float msk[2][9];
#pragma unroll
    for (int h = 0; h < 2; ++h) {
        const int A = h ? A1 : A0;
#pragma unroll
        for (int dy = 0; dy < 3; ++dy) {
#pragma unroll
            for (int dx = 0; dx < 3; ++dx) {
                const int iy = A - 1 + dy, ix = C - 1 + dx;
                const bool v = (iy >= 0) && (iy < HIN) && (ix >= 0) && (ix < WIN);
                offs[h][dy * 3 + dx] = v ? iy * WIN + ix : 0;
                msk[h][dy * 3 + dx] = v ? 1.f : 0.f;
            }
        }
    }

    float acc[2][4 * OCT];
#pragma unroll
    for (int h = 0; h < 2; ++h)
#pragma unroll
        for (int j = 0; j < 4 * OCT; ++j) acc[h][j] = 0.f;

    for (int ic0 = 0; ic0 < CIN; ic0 += ICC) {
        __syncthreads();
        for (int t = tid; t < ICC * 16 * OCT; t += 256) {
            int oc_l = t % OCT, r = t / OCT, k = r & 15, ic_l = r >> 4;
            sw[(ic_l * 16 + k) * OCT + oc_l] =
                w[((size_t)(ic0 + ic_l) * COUT + oc0 + oc_l) * 16 + k];
        }
        __syncthreads();
#pragma unroll 1
        for (int ic_l = 0; ic_l < ICC; ++ic_l) {
            const float* ip = in + (size_t)(n * CIN + ic0 + ic_l) * HIN * WIN;
            float in9[2][9];
#pragma unroll
            for (int h = 0; h < 2; ++h)
#pragma unroll
                for (int j = 0; j < 9; ++j) {
                    float v = ip[offs[h][j]] * msk[h][j];
                    if (INL) v = lrelu_in(v);
                    in9[h][j] = v;
                }
#pragma unroll
            for (int ky = 0; ky < 4; ++ky) {
                const int ry = (ky + 1) & 1;
                const int dy = 2 - ((ky + 1) >> 1);
#pragma unroll
                for (int kx = 0; kx < 4; ++kx) {
                    const int rx = (kx + 1) & 1;
                    const int dx = 2 - ((kx + 1) >> 1);
                    const float va = in9[0][dy * 3 + dx];
                    const float vb = in9[1][dy * 3 + dx];
                    const int po = ry * 2 + rx;
                    const float4* wp = (const float4*)&sw[(ic_l * 16 + ky * 4 + kx) * OCT];
#pragma unroll
                    for (int q4 = 0; q4 < OCT / 4; ++q4) {
                        float4 wv = wp[q4];
                        acc[0][po * OCT + q4 * 4 + 0] = fmaf(wv.x, va, acc[0][po * OCT + q4 * 4 + 0]);
                        acc[0][po * OCT + q4 * 4 + 1] = fmaf(wv.y, va, acc[0][po * OCT + q4 * 4 + 1]);
                        acc[0][po * OCT + q4 * 4 + 2] = fmaf(wv.z, va, acc[0][po * OCT + q4 * 4 + 2]);
                        acc[0][po * OCT + q4 * 4 + 3] = fmaf(wv.w, va, acc[0][po * OCT + q4 * 4 + 3]);
                        acc[1][po * OCT + q4 * 4 + 0] = fmaf(wv.x, vb, acc[1][po * OCT + q4 * 4 + 0]);
                        acc[1][po * OCT + q4 * 4 + 1] = fmaf(wv.y, vb, acc[1][po * OCT + q4 * 4 + 1]);
                        acc[1][po * OCT + q4 * 4 + 2] = fmaf(wv.z, vb, acc[1][po * OCT + q4 * 4 + 2]);
                        acc[1][po * OCT + q4 * 4 + 3] = fmaf(wv.w, vb, acc[1][po * OCT + q4 * 4 + 3]);
                    }
                }
            }
        }
    }
#pragma unroll
    for (int h = 0; h < 2; ++h) {
        const int A = h ? A1 : A0;
#pragma unroll
        for (int po = 0; po < 4; ++po) {
            const int ry = po >> 1, rx = po & 1;
            const int oy = 2 * A + ry, ox = 2 * C + rx;
#pragma unroll
            for (int j = 0; j < OCT; ++j) {
                float r = acc[h][po * OCT + j] + bias[oc0 + j];
                r = actf<ACT>(r);
                out[((size_t)(n * COUT + oc0 + j) * HOUT + oy) * WOUT + ox] = r;
            }
        }
    }
}

// ---------------------------------------------------------------------------
// Codebook norms, precomputed once. (validated R7/R8)
// ---------------------------------------------------------------------------
__global__ void norm_k(const float* __restrict__ cb, float* __restrict__ nrm) {
    const int c = blockIdx.x * 256 + threadIdx.x;   // 0..2047
    const float4* p = (const float4*)(cb + (size_t)c * 64);
    float a0 = 0.f, a1 = 0.f, a2 = 0.f, a3 = 0.f;
#pragma unroll
    for (int i = 0; i < 16; ++i) {
        float4 v = p[i];
        a0 = fmaf(v.x, v.x, a0); a1 = fmaf(v.y, v.y, a1);
        a2 = fmaf(v.z, v.z, a2); a3 = fmaf(v.w, v.w, a3);
    }
    nrm[c] = (a0 + a1) + (a2 + a3);
}

// ---------------------------------------------------------------------------
// Residual VQ v5 (NT=2 register blocking + 4-way code split). Validated R18:
// 402us, Occ 21.4, VALUBusy 51. NUMERICS: exact validated chains.
// ---------------------------------------------------------------------------
__launch_bounds__(256, 2)
__global__ void rvq_k(const float* __restrict__ z, const float* __restrict__ cb,
                      const float* __restrict__ nrm,
                      float* __restrict__ q, float* __restrict__ idx_out,
                      float* __restrict__ loss_acc)
{
    __shared__ float scb[256 * 64];     // 64 KB: 256 staged code rows
    __shared__ float snrm[256];
    __shared__ float lmin[4][2][64];    // [wave][token-slot][lane]
    __shared__ int   lidx[4][2][64];
    const int tid = threadIdx.x;
    const int lane = tid & 63;
    const int w = __builtin_amdgcn_readfirstlane(tid >> 6);   // wave id 0..3
    const int t0 = blockIdx.x * 128 + lane;                    // slot-0 token
    const int t1 = t0 + 64;                                    // slot-1 token

    float r0[64], r1[64];
    {
        const float4* zp0 = (const float4*)(z + (size_t)t0 * 64);
        const float4* zp1 = (const float4*)(z + (size_t)t1 * 64);
#pragma unroll
        for (int i = 0; i < 16; ++i) {
            float4 v = zp0[i];
            r0[4 * i + 0] = v.x; r0[4 * i + 1] = v.y;
            r0[4 * i + 2] = v.z; r0[4 * i + 3] = v.w;
            float4 u = zp1[i];
            r1[4 * i + 0] = u.x; r1[4 * i + 1] = u.y;
            r1[4 * i + 2] = u.z; r1[4 * i + 3] = u.w;
        }
    }

    for (int s = 0; s < 4; ++s) {
        float sr20, sr21;
        {
            float a0 = 0.f, a1 = 0.f, a2 = 0.f, a3 = 0.f;
            float b0 = 0.f, b1 = 0.f, b2 = 0.f, b3 = 0.f;
#pragma unroll
            for (int i = 0; i < 32; i += 4) {
                a0 = fmaf(r0[i + 0], r0[i + 0], a0);
                a1 = fmaf(r0[i + 1], r0[i + 1], a1);
                a2 = fmaf(r0[i + 2], r0[i + 2], a2);
                a3 = fmaf(r0[i + 3], r0[i + 3], a3);
                b0 = fmaf(r0[32 + i + 0], r0[32 + i + 0], b0);
                b1 = fmaf(r0[32 + i + 1], r0[32 + i + 1], b1);
                b2 = fmaf(r0[32 + i + 2], r0[32 + i + 2], b2);
                b3 = fmaf(r0[32 + i + 3], r0[32 + i + 3], b3);
            }
            sr20 = ((a0 + a1) + (a2 + a3)) + ((b0 + b1) + (b2 + b3));
        }
        {
            float a0 = 0.f, a1 = 0.f, a2 = 0.f, a3 = 0.f;
            float b0 = 0.f, b1 = 0.f, b2 = 0.f, b3 = 0.f;
#pragma unroll
            for (int i = 0; i < 32; i += 4) {
                a0 = fmaf(r1[i + 0], r1[i + 0], a0);
                a1 = fmaf(r1[i + 1], r1[i + 1], a1);
                a2 = fmaf(r1[i + 2], r1[i + 2], a2);
                a3 = fmaf(r1[i + 3], r1[i + 3], a3);
                b0 = fmaf(r1[32 + i + 0], r1[32 + i + 0], b0);
                b1 = fmaf(r1[32 + i + 1], r1[32 + i + 1], b1);
                b2 = fmaf(r1[32 + i + 2], r1[32 + i + 2], b2);
                b3 = fmaf(r1[32 + i + 3], r1[32 + i + 3], b3);
            }
            sr21 = ((a0 + a1) + (a2 + a3)) + ((b0 + b1) + (b2 + b3));
        }

        float dmin0 = 3.4e38f, dmin1 = 3.4e38f;
        int best0 = 0, best1 = 0;

        for (int pass = 0; pass < 2; ++pass) {
            __syncthreads();
            {
                const float4* csrc = (const float4*)(cb + (size_t)s * 512 * 64);
                for (int i = tid; i < 4096; i += 256) {
                    const int row = i >> 4, f4 = i & 15;
                    const int grow = (row >> 6) * 128 + pass * 64 + (row & 63);
                    ((float4*)scb)[row * 16 + f4] = csrc[(size_t)grow * 16 + f4];
                }
                const int g = (tid >> 6) * 128 + pass * 64 + (tid & 63);
                snrm[tid] = nrm[s * 512 + g];
            }
            __syncthreads();

#pragma unroll 2
            for (int kk = 0; kk < 64; ++kk) {
                const float4* cp = (const float4*)&scb[(size_t)(w * 64 + kk) * 64];
                float a0 = 0.f, a1 = 0.f, a2 = 0.f, a3 = 0.f;
                float e0 = 0.f, e1 = 0.f, e2 = 0.f, e3 = 0.f;
#pragma unroll
                for (int i = 0; i < 8; ++i) {
                    float4 c = cp[i];
                    a0 = fmaf(r0[4 * i + 0], c.x, a0);
                    a1 = fmaf(r0[4 * i + 1], c.y, a1);
                    a2 = fmaf(r0[4 * i + 2], c.z, a2);
                    a3 = fmaf(r0[4 * i + 3], c.w, a3);
                    e0 = fmaf(r1[4 * i + 0], c.x, e0);
                    e1 = fmaf(r1[4 * i + 1], c.y, e1);
                    e2 = fmaf(r1[4 * i + 2], c.z, e2);
                    e3 = fmaf(r1[4 * i + 3], c.w, e3);
                }
                float b0 = 0.f, b1 = 0.f, b2 = 0.f, b3 = 0.f;
                float f0 = 0.f, f1 = 0.f, f2 = 0.f, f3 = 0.f;
#pragma unroll
                for (int i = 0; i < 8; ++i) {
                    float4 c = cp[8 + i];
                    b0 = fmaf(r0[32 + 4 * i + 0], c.x, b0);
                    b1 = fmaf(r0[32 + 4 * i + 1], c.y, b1);
                    b2 = fmaf(r0[32 + 4 * i + 2], c.z, b2);
                    b3 = fmaf(r0[32 + 4 * i + 3], c.w, b3);
                    f0 = fmaf(r1[32 + 4 * i + 0], c.x, f0);
                    f1 = fmaf(r1[32 + 4 * i + 1], c.y, f1);
                    f2 = fmaf(r1[32 + 4 * i + 2], c.z, f2);
                    f3 = fmaf(r1[32 + 4 * i + 3], c.w, f3);
                }
                const float dot0 = ((a0 + a1) + (a2 + a3)) + ((b0 + b1) + (b2 + b3));
                const float dot1 = ((e0 + e1) + (e2 + e3)) + ((f0 + f1) + (f2 + f3));
                const float nk = snrm[w * 64 + kk];
                const float d0 = fmaf(-2.f, dot0, sr20) + nk;
                const float d1 = fmaf(-2.f, dot1, sr21) + nk;
                const int kl = pass * 64 + kk;
                if (d0 < dmin0) { dmin0 = d0; best0 = kl; }
                if (d1 < dmin1) { dmin1 = d1; best1 = kl; }
            }
        }

        lmin[w][0][lane] = dmin0; lidx[w][0][lane] = best0 + w * 128;
        lmin[w][1][lane] = dmin1; lidx[w][1][lane] = best1 + w * 128;
        __syncthreads();
        float d0c = lmin[0][0][lane]; int b0c = lidx[0][0][lane];
        float d1c = lmin[0][1][lane]; int b1c = lidx[0][1][lane];
#pragma unroll
        for (int ww = 1; ww < 4; ++ww) {
            const float dd0 = lmin[ww][0][lane]; const int ii0 = lidx[ww][0][lane];
            if (dd0 < d0c) { d0c = dd0; b0c = ii0; }
            const float dd1 = lmin[ww][1][lane]; const int ii1 = lidx[ww][1][lane];
            if (dd1 < d1c) { d1c = dd1; b1c = ii1; }
        }

        if (w < 2) {
            float lv = (w == 0) ? d0c : d1c;
#pragma unroll
            for (int off = 32; off; off >>= 1) lv += __shfl_down(lv, off, 64);
            if (lane == 0) atomicAdd(&loss_acc[s], lv);
        }
        if (w == 0)      idx_out[(size_t)t0 * 4 + s] = (float)b0c;
        else if (w == 1) idx_out[(size_t)t1 * 4 + s] = (float)b1c;

        const float4* c0 = (const float4*)(cb + ((size_t)s * 512 + b0c) * 64);
        const float4* c1 = (const float4*)(cb + ((size_t)s * 512 + b1c) * 64);
#pragma unroll
        for (int i = 0; i < 16; ++i) {
            float4 v = c0[i];
            r0[4 * i + 0] -= v.x; r0[4 * i + 1] -= v.y;
            r0[4 * i + 2] -= v.z; r0[4 * i + 3] -= v.w;
            float4 u = c1[i];
            r1[4 * i + 0] -= u.x; r1[4 * i + 1] -= u.y;
            r1[4 * i + 2] -= u.z; r1[4 * i + 3] -= u.w;
        }
    }

    if (w == 0) {
        const float4* zp = (const float4*)(z + (size_t)t0 * 64);
        const int n = t0 >> 12, pix = t0 & 4095;
        float* qp = q + (size_t)n * 64 * 4096 + pix;
#pragma unroll
        for (int i = 0; i < 16; ++i) {
            float4 v = zp[i];
            qp[(size_t)(4 * i + 0) * 4096] = v.x - r0[4 * i + 0];
            qp[(size_t)(4 * i + 1) * 4096] = v.y - r0[4 * i + 1];
            qp[(size_t)(4 * i + 2) * 4096] = v.z - r0[4 * i + 2];
            qp[(size_t)(4 * i + 3) * 4096] = v.w - r0[4 * i + 3];
        }
    } else if (w == 1) {
        const float4* zp = (const float4*)(z + (size_t)t1 * 64);
        const int n = t1 >> 12, pix = t1 & 4095;
        float* qp = q + (size_t)n * 64 * 4096 + pix;
#pragma unroll
        for (int i = 0; i < 16; ++i) {
            float4 v = zp[i];
            qp[(size_t)(4 * i + 0) * 4096] = v.x - r1[4 * i + 0];
            qp[(size_t)(4 * i + 1) * 4096] = v.y - r1[4 * i + 1];
            qp[(size_t)(4 * i + 2) * 4096] = v.z - r1[4 * i + 2];
            qp[(size_t)(4 * i + 3) * 4096] = v.w - r1[4 * i + 3];
        }
    }
}

__global__ void init_k(float* loss_acc) {
    if (threadIdx.x < 4) loss_acc[threadIdx.x] = 0.f;
}
__global__ void fin_k(const float* __restrict__ loss_acc, float* __restrict__ out_loss) {
    if (threadIdx.x < 4)
        out_loss[threadIdx.x] = loss_acc[threadIdx.x] * (0.25f / 4194304.f); // BETA/(N*D)
}

// ---------------------------------------------------------------------------
extern "C" void kernel_launch(void* const* d_in, const int* in_sizes, int n_in,
                              void* d_out, int out_size, void* d_ws, size_t ws_size,
                              hipStream_t stream)
{
    const float* x    = (const float*)d_in[0];
    const float* e1w  = (const float*)d_in[1];  const float* e1b = (const float*)d_in[2];
    const float* e2w  = (const float*)d_in[3];  const float* e2b = (const float*)d_in[4];
    const float* e3w  = (const float*)d_in[5];  const float* e3b = (const float*)d_in[6];
    const float* r1aw = (const float*)d_in[7];  const float* r1bw = (const float*)d_in[8];
    const float* r2aw = (const float*)d_in[9];  const float* r2bw = (const float*)d_in[10];
    const float* e4w  = (const float*)d_in[11]; const float* e4b = (const float*)d_in[12];
    const float* cbs  = (const float*)d_in[13];
    const float* d1w  = (const float*)d_in[14]; const float* d1b = (const float*)d_in[15];
    const float* dr1aw= (const float*)d_in[16]; const float* dr1bw = (const float*)d_in[17];
    const float* dr2aw= (const float*)d_in[18]; const float* dr2bw = (const float*)d_in[19];
    const float* dt1w = (const float*)d_in[20]; const float* dt1b = (const float*)d_in[21];
    const float* dt2w = (const float*)d_in[22]; const float* dt2b = (const float*)d_in[23];

    float* out = (float*)d_out;
    float* ws  = (float*)d_ws;

    float* BIG = ws;                    // 16.78M floats (e1 out / dt1 out)
    float* P2  = BIG;
    float* P3  = BIG + 8388608;
    float* P1  = ws + 16777216;
    float* Z   = ws + 25165824;
    float* Q   = ws + 29360128;
    float* LACC= ws + 33554432;         // 4 floats
    float* NRM = ws + 33554448;         // 2048 floats

    float* out_recons = out;                    // 16*4*256*256 = 4194304
    float* out_idx    = out + 4194304;          // 16*64*64*4   = 262144
    float* out_loss   = out + 4194304 + 262144; // 4

    init_k<<<1, 64, 0, stream>>>(LACC);
    norm_k<<<8, 256, 0, stream>>>(cbs, NRM);

    // ---- encoder ----
    conv_k<4, 64, 4, 2, 1, 256, 256, 128, 128, 4, 2, 2, true>
        <<<dim3(32, 4, 16), 256, 0, stream>>>(x, e1w, e1b, BIG);
    // e2: NPY=4, OCT=8, 3 blocks/CU (R22). Block = 16 cols x 64 rows x 8 oc.
    // grid: TW=4 x (64/64=1) = 4, 128/8 = 16, 16
    conv_oct_k<64, 128, 4, 2, 1, 128, 128, 64, 64, 16, 4, 8, 3, 2, true>
        <<<dim3(4, 16, 16), 256, 0, stream>>>(BIG, e2w, e2b, P1);
    conv3_k<128, 128, 16, 2, true>
        <<<dim3(2, 16, 16), 256, 0, stream>>>(P1, e3w, e3b, P2);
    conv3_k<128, 128, 16, 1, false>
        <<<dim3(2, 16, 16), 256, 0, stream>>>(P2, r1aw, nullptr, P3);
    conv1x1_k<128, 128, 4, 0, false, false, true, false>
        <<<dim3(4, 8, 16), 256, 0, stream>>>(P3, r1bw, nullptr, P2, P1);
    conv3_k<128, 128, 16, 1, false>
        <<<dim3(2, 16, 16), 256, 0, stream>>>(P1, r2aw, nullptr, P3);
    conv1x1_k<128, 128, 4, 0, false, false, true, false>
        <<<dim3(4, 8, 16), 256, 0, stream>>>(P3, r2bw, nullptr, P1, P2);
    conv1x1_k<128, 64, 2, 2, true, true, false, true>
        <<<dim3(8, 4, 16), 256, 0, stream>>>(P2, e4w, e4b, nullptr, Z);

    // ---- residual VQ ----
    rvq_k<<<512, 256, 0, stream>>>(Z, cbs, NRM, Q, out_idx, LACC);
    fin_k<<<1, 64, 0, stream>>>(LACC, out_loss);

    // ---- decoder ----
    conv3_k<64, 128, 16, 2, true>
        <<<dim3(2, 16, 16), 256, 0, stream>>>(Q, d1w, d1b, P1);
    conv3_k<128, 128, 16, 1, false>
        <<<dim3(2, 16, 16), 256, 0, stream>>>(P1, dr1aw, nullptr, P2);
    conv1x1_k<128, 128, 4, 0, false, false, true, false>
        <<<dim3(4, 8, 16), 256, 0, stream>>>(P2, dr1bw, nullptr, P1, P3);
    conv3_k<128, 128, 16, 1, false>
        <<<dim3(2, 16, 16), 256, 0, stream>>>(P3, dr2aw, nullptr, P2);
    conv1x1_k<128, 128, 4, 0, false, false, true, false>
        <<<dim3(4, 8, 16), 256, 0, stream>>>(P2, dr2bw, nullptr, P3, P1);
    // dt1: OCT=8, 2 A-rows/thread -> grid (TBW=4 x 2 A-tiles = 8, 64/8 = 8, 16)
    convt_k<128, 64, 8, 64, 8, 2, true>
        <<<dim3(8, 8, 16), 256, 0, stream>>>(P1, dt1w, dt1b, BIG);
    // dt2: OCT=4 -> grid (TBW=8 x 4 A-tiles = 32, 1, 16)
    convt_k<64, 4, 4, 128, 16, 1, false>
        <<<dim3(32, 1, 16), 256, 0, stream>>>(BIG, dt2w, dt2b, out_recons);
}

// Round 10
// 2794.269 us; speedup vs baseline: 1.1339x; 1.1339x over previous
//
#include <hip/hip_runtime.h>
#include <cstddef>

// ---------------------------------------------------------------------------
// RQ-VAE forward on MI355X. Round 23: REVERT convt_k to validated (256,2).
// R22 post-mortem: (256,3) on convt squeezed VGPR to 84 < ~110 live values ->
// accumulator spilled to scratch (WRITE_SIZE 397MB vs 67MB output, 735us).
// RULE: never set min-waves that pushes the VGPR cap below acc+patch+~40.
// e2's conv_oct_k (NPY=4/OCT=8, acc=32, genuinely spill-safe) KEPT to
// isolate its effect this round (R22 wrongly bundled two changes).
// rvq_k (R18), conv3_k (R21), conv1x1_k, e1 conv_k unchanged.
// ---------------------------------------------------------------------------

template<int ACT> __device__ __forceinline__ float actf(float v) {
    if constexpr (ACT == 1) return v > 0.f ? v : 0.f;            // relu
    else if constexpr (ACT == 2) return v > 0.f ? v : 0.01f * v; // leaky relu
    else return v;
}
__device__ __forceinline__ float lrelu_in(float v) { return v > 0.f ? v : 0.01f * v; }

// ---------------------------------------------------------------------------
// Direct conv (e1): thread = NPY rows x 16 oc. (validated R8)
// ---------------------------------------------------------------------------
template<int CIN, int COUT, int K, int S, int P, int HIN, int WIN, int HOUT, int WOUT,
         int ICC, int NPY, int ACT, bool BIAS>
__launch_bounds__(256, (NPY >= 4 ? 2 : 4))
__global__ void conv_k(const float* __restrict__ in, const float* __restrict__ w,
                       const float* __restrict__ bias, float* __restrict__ out)
{
    constexpr int K2 = K * K;
    constexpr int NR = S * (NPY - 1) + K;
    constexpr int BH = 16 * NPY;
    __shared__ float sw[ICC * K2 * 16];
    const int tid = threadIdx.x;
    const int tx = tid & 15, ty = tid >> 4;
    constexpr int TW = WOUT / 16;
    const int bx = blockIdx.x % TW, by = blockIdx.x / TW;
    const int ox = bx * 16 + tx;
    const int oy0 = by * BH + ty * NPY;
    const int oc0 = blockIdx.y * 16;
    const int n = blockIdx.z;
    const int ix0 = ox * S - P, iy0 = oy0 * S - P;

    int ro[NR]; float mr[NR];
#pragma unroll
    for (int r = 0; r < NR; ++r) {
        const int iy = iy0 + r;
        const bool v = (iy >= 0) && (iy < HIN);
        ro[r] = v ? iy * WIN : 0;
        mr[r] = v ? 1.f : 0.f;
    }
    int co[K]; float mc[K];
#pragma unroll
    for (int c = 0; c < K; ++c) {
        const int ix = ix0 + c;
        const bool v = (ix >= 0) && (ix < WIN);
        co[c] = v ? ix : 0;
        mc[c] = v ? 1.f : 0.f;
    }

    float acc[NPY][16];
#pragma unroll
    for (int py = 0; py < NPY; ++py)
#pragma unroll
        for (int j = 0; j < 16; ++j) acc[py][j] = 0.f;

    for (int ic0 = 0; ic0 < CIN; ic0 += ICC) {
        __syncthreads();
        for (int t = tid; t < ICC * K2 * 16; t += 256) {
            int oc_l = t & 15, r = t >> 4, k = r % K2, ic_l = r / K2;
            sw[(ic_l * K2 + k) * 16 + oc_l] =
                w[((size_t)(oc0 + oc_l) * CIN + ic0 + ic_l) * K2 + k];
        }
        __syncthreads();
#pragma unroll 1
        for (int ic_l = 0; ic_l < ICC; ++ic_l) {
            const float* ip = in + (size_t)(n * CIN + ic0 + ic_l) * HIN * WIN;
            float patch[NR][K];
#pragma unroll
            for (int r = 0; r < NR; ++r)
#pragma unroll
                for (int c = 0; c < K; ++c)
                    patch[r][c] = ip[ro[r] + co[c]] * (mr[r] * mc[c]);
            const float* swp = &sw[ic_l * K2 * 16];
#pragma unroll
            for (int ky = 0; ky < K; ++ky) {
#pragma unroll
                for (int kx = 0; kx < K; ++kx) {
                    const float4* wp = (const float4*)&swp[(ky * K + kx) * 16];
                    float4 w0 = wp[0], w1 = wp[1], w2 = wp[2], w3 = wp[3];
#pragma unroll
                    for (int py = 0; py < NPY; ++py) {
                        const float v = patch[py * S + ky][kx];
                        acc[py][0]  = fmaf(w0.x, v, acc[py][0]);
                        acc[py][1]  = fmaf(w0.y, v, acc[py][1]);
                        acc[py][2]  = fmaf(w0.z, v, acc[py][2]);
                        acc[py][3]  = fmaf(w0.w, v, acc[py][3]);
                        acc[py][4]  = fmaf(w1.x, v, acc[py][4]);
                        acc[py][5]  = fmaf(w1.y, v, acc[py][5]);
                        acc[py][6]  = fmaf(w1.z, v, acc[py][6]);
                        acc[py][7]  = fmaf(w1.w, v, acc[py][7]);
                        acc[py][8]  = fmaf(w2.x, v, acc[py][8]);
                        acc[py][9]  = fmaf(w2.y, v, acc[py][9]);
                        acc[py][10] = fmaf(w2.z, v, acc[py][10]);
                        acc[py][11] = fmaf(w2.w, v, acc[py][11]);
                        acc[py][12] = fmaf(w3.x, v, acc[py][12]);
                        acc[py][13] = fmaf(w3.y, v, acc[py][13]);
                        acc[py][14] = fmaf(w3.z, v, acc[py][14]);
                        acc[py][15] = fmaf(w3.w, v, acc[py][15]);
                    }
                }
            }
        }
    }
#pragma unroll
    for (int py = 0; py < NPY; ++py) {
#pragma unroll
        for (int j = 0; j < 16; ++j) {
            float r = acc[py][j];
            if (BIAS) r += bias[oc0 + j];
            r = actf<ACT>(r);
            out[((size_t)(n * COUT + oc0 + j) * HOUT + oy0 + py) * WOUT + ox] = r;
        }
    }
}

// ---------------------------------------------------------------------------
// conv_oct_k (R22, e2): thread = NPY rows x OCT oc; OCT=8, acc=32 floats,
// launch_bounds(256,3) spill-safe. (kept from R22 to isolate its effect)
// ---------------------------------------------------------------------------
template<int CIN, int COUT, int K, int S, int P, int HIN, int WIN, int HOUT, int WOUT,
         int ICC, int NPY, int OCT, int MINW, int ACT, bool BIAS>
__launch_bounds__(256, MINW)
__global__ void conv_oct_k(const float* __restrict__ in, const float* __restrict__ w,
                           const float* __restrict__ bias, float* __restrict__ out)
{
    constexpr int K2 = K * K;
    constexpr int NR = S * (NPY - 1) + K;
    constexpr int BH = 16 * NPY;
    __shared__ float sw[ICC * K2 * OCT];
    const int tid = threadIdx.x;
    const int tx = tid & 15, ty = tid >> 4;
    constexpr int TW = WOUT / 16;
    const int bx = blockIdx.x % TW, by = blockIdx.x / TW;
    const int ox = bx * 16 + tx;
    const int oy0 = by * BH + ty * NPY;
    const int oc0 = blockIdx.y * OCT;
    const int n = blockIdx.z;
    const int ix0 = ox * S - P, iy0 = oy0 * S - P;

    int ro[NR]; float mr[NR];
#pragma unroll
    for (int r = 0; r < NR; ++r) {
        const int iy = iy0 + r;
        const bool v = (iy >= 0) && (iy < HIN);
        ro[r] = v ? iy * WIN : 0;
        mr[r] = v ? 1.f : 0.f;
    }
    int co[K]; float mc[K];
#pragma unroll
    for (int c = 0; c < K; ++c) {
        const int ix = ix0 + c;
        const bool v = (ix >= 0) && (ix < WIN);
        co[c] = v ? ix : 0;
        mc[c] = v ? 1.f : 0.f;
    }

    float acc[NPY][OCT];
#pragma unroll
    for (int py = 0; py < NPY; ++py)
#pragma unroll
        for (int j = 0; j < OCT; ++j) acc[py][j] = 0.f;

    for (int ic0 = 0; ic0 < CIN; ic0 += ICC) {
        __syncthreads();
        for (int t = tid; t < ICC * K2 * OCT; t += 256) {
            int oc_l = t % OCT, r = t / OCT, k = r % K2, ic_l = r / K2;
            sw[(ic_l * K2 + k) * OCT + oc_l] =
                w[((size_t)(oc0 + oc_l) * CIN + ic0 + ic_l) * K2 + k];
        }
        __syncthreads();
#pragma unroll 1
        for (int ic_l = 0; ic_l < ICC; ++ic_l) {
            const float* ip = in + (size_t)(n * CIN + ic0 + ic_l) * HIN * WIN;
            float patch[NR][K];
#pragma unroll
            for (int r = 0; r < NR; ++r)
#pragma unroll
                for (int c = 0; c < K; ++c)
                    patch[r][c] = ip[ro[r] + co[c]] * (mr[r] * mc[c]);
            const float* swp = &sw[ic_l * K2 * OCT];
#pragma unroll
            for (int ky = 0; ky < K; ++ky) {
#pragma unroll
                for (int kx = 0; kx < K; ++kx) {
                    const float4* wp = (const float4*)&swp[(ky * K + kx) * OCT];
#pragma unroll
                    for (int q4 = 0; q4 < OCT / 4; ++q4) {
                        const float4 wv = wp[q4];
#pragma unroll
                        for (int py = 0; py < NPY; ++py) {
                            const float v = patch[py * S + ky][kx];
                            acc[py][q4 * 4 + 0] = fmaf(wv.x, v, acc[py][q4 * 4 + 0]);
                            acc[py][q4 * 4 + 1] = fmaf(wv.y, v, acc[py][q4 * 4 + 1]);
                            acc[py][q4 * 4 + 2] = fmaf(wv.z, v, acc[py][q4 * 4 + 2]);
                            acc[py][q4 * 4 + 3] = fmaf(wv.w, v, acc[py][q4 * 4 + 3]);
                        }
                    }
                }
            }
        }
    }
#pragma unroll
    for (int py = 0; py < NPY; ++py) {
#pragma unroll
        for (int j = 0; j < OCT; ++j) {
            float r = acc[py][j];
            if (BIAS) r += bias[oc0 + j];
            r = actf<ACT>(r);
            out[((size_t)(n * COUT + oc0 + j) * HOUT + oy0 + py) * WOUT + ox] = r;
        }
    }
}

// ---------------------------------------------------------------------------
// conv3_k: 3x3 s1 p1 on 64x64 maps, OCT=8 oc x NPY=8 rows per thread.
// (validated R21; near its 2-wave/SIMD VALU floor)
// ---------------------------------------------------------------------------
template<int CIN, int COUT, int ICC, int ACT, bool BIAS>
__launch_bounds__(256, 2)
__global__ void conv3_k(const float* __restrict__ in, const float* __restrict__ w,
                        const float* __restrict__ bias, float* __restrict__ out)
{
    constexpr int HW = 64;
    __shared__ float sw[ICC * 9 * 8];
    const int tid = threadIdx.x;
    const int tx = tid & 31, ty = tid >> 5;     // 32 x 8
    const int ox = blockIdx.x * 32 + tx;
    const int oy0 = ty * 8;
    const int oc0 = blockIdx.y * 8;
    const int n = blockIdx.z;

    int ro[10]; float mr[10];
#pragma unroll
    for (int r = 0; r < 10; ++r) {
        const int iy = oy0 - 1 + r;
        const bool v = (iy >= 0) && (iy < HW);
        ro[r] = v ? iy * HW : 0;
        mr[r] = v ? 1.f : 0.f;
    }
    int co[3]; float mc[3];
#pragma unroll
    for (int c = 0; c < 3; ++c) {
        const int ix = ox - 1 + c;
        const bool v = (ix >= 0) && (ix < HW);
        co[c] = v ? ix : 0;
        mc[c] = v ? 1.f : 0.f;
    }

    float acc[8][8];
#pragma unroll
    for (int py = 0; py < 8; ++py)
#pragma unroll
        for (int j = 0; j < 8; ++j) acc[py][j] = 0.f;

    for (int ic0 = 0; ic0 < CIN; ic0 += ICC) {
        __syncthreads();
        for (int t = tid; t < ICC * 9 * 8; t += 256) {
            int oc_l = t & 7, r = t >> 3, k = r % 9, ic_l = r / 9;
            sw[(ic_l * 9 + k) * 8 + oc_l] =
                w[((size_t)(oc0 + oc_l) * CIN + ic0 + ic_l) * 9 + k];
        }
        __syncthreads();
#pragma unroll 1
        for (int ic_l = 0; ic_l < ICC; ++ic_l) {
            const float* ip = in + (size_t)(n * CIN + ic0 + ic_l) * HW * HW;
            float patch[10][3];
#pragma unroll
            for (int r = 0; r < 10; ++r)
#pragma unroll
                for (int c = 0; c < 3; ++c)
                    patch[r][c] = ip[ro[r] + co[c]] * (mr[r] * mc[c]);
            const float* swp = &sw[ic_l * 9 * 8];
#pragma unroll
            for (int ky = 0; ky < 3; ++ky) {
#pragma unroll
                for (int kx = 0; kx < 3; ++kx) {
                    const float4* wp = (const float4*)&swp[(ky * 3 + kx) * 8];
                    float4 w0 = wp[0], w1 = wp[1];
#pragma unroll
                    for (int py = 0; py < 8; ++py) {
                        const float v = patch[py + ky][kx];
                        acc[py][0] = fmaf(w0.x, v, acc[py][0]);
                        acc[py][1] = fmaf(w0.y, v, acc[py][1]);
                        acc[py][2] = fmaf(w0.z, v, acc[py][2]);
                        acc[py][3] = fmaf(w0.w, v, acc[py][3]);
                        acc[py][4] = fmaf(w1.x, v, acc[py][4]);
                        acc[py][5] = fmaf(w1.y, v, acc[py][5]);
                        acc[py][6] = fmaf(w1.z, v, acc[py][6]);
                        acc[py][7] = fmaf(w1.w, v, acc[py][7]);
                    }
                }
            }
        }
    }
#pragma unroll
    for (int py = 0; py < 8; ++py) {
#pragma unroll
        for (int j = 0; j < 8; ++j) {
            float r = acc[py][j];
            if (BIAS) r += bias[oc0 + j];
            r = actf<ACT>(r);
            out[((size_t)(n * COUT + oc0 + j) * HW + oy0 + py) * HW + ox] = r;
        }
    }
}

// ---------------------------------------------------------------------------
// 1x1 conv over 64x64 maps (HW=4096), NPX pixels per thread. (validated R8)
// ---------------------------------------------------------------------------
template<int CIN, int COUT, int NPX, int ACT, bool BIAS, bool INL, bool RESID, bool TOK>
__launch_bounds__(256, 3)
__global__ void conv1x1_k(const float* __restrict__ in, const float* __restrict__ w,
                          const float* __restrict__ bias, const float* __restrict__ resid,
                          float* __restrict__ out)
{
    constexpr int HW = 4096;
    __shared__ float sw[16 * CIN];
    const int tid = threadIdx.x;
    const int base = blockIdx.x * (256 * NPX) + tid;
    const int oc0 = blockIdx.y * 16;
    const int n = blockIdx.z;

    for (int t = tid; t < 16 * CIN; t += 256) {
        int oc_l = t & 15, ic = t >> 4;
        sw[ic * 16 + oc_l] = w[(size_t)(oc0 + oc_l) * CIN + ic];
    }
    __syncthreads();

    float acc[NPX][16];
#pragma unroll
    for (int p = 0; p < NPX; ++p)
#pragma unroll
        for (int j = 0; j < 16; ++j) acc[p][j] = 0.f;

    const float* ip = in + (size_t)n * CIN * HW;
#pragma unroll 2
    for (int ic = 0; ic < CIN; ++ic) {
        float v[NPX];
#pragma unroll
        for (int p = 0; p < NPX; ++p) {
            float t = ip[(size_t)ic * HW + base + 256 * p];
            if (INL) t = lrelu_in(t);
            v[p] = t;
        }
        const float4* wp = (const float4*)&sw[ic * 16];
#pragma unroll
        for (int q4 = 0; q4 < 4; ++q4) {
            const float4 wv = wp[q4];
#pragma unroll
            for (int p = 0; p < NPX; ++p) {
                acc[p][q4 * 4 + 0] = fmaf(wv.x, v[p], acc[p][q4 * 4 + 0]);
                acc[p][q4 * 4 + 1] = fmaf(wv.y, v[p], acc[p][q4 * 4 + 1]);
                acc[p][q4 * 4 + 2] = fmaf(wv.z, v[p], acc[p][q4 * 4 + 2]);
                acc[p][q4 * 4 + 3] = fmaf(wv.w, v[p], acc[p][q4 * 4 + 3]);
            }
        }
    }
#pragma unroll
    for (int p = 0; p < NPX; ++p) {
        const int pix = base + 256 * p;
#pragma unroll
        for (int j = 0; j < 16; ++j) {
            float r = acc[p][j];
            if (BIAS) r += bias[oc0 + j];
            r = actf<ACT>(r);
            if (RESID) r += resid[((size_t)(n * COUT + oc0 + j)) * HW + pix];
            if (TOK)
                out[((size_t)n * HW + pix) * COUT + oc0 + j] = r;
            else
                out[((size_t)(n * COUT + oc0 + j)) * HW + pix] = r;
        }
    }
}

// ---------------------------------------------------------------------------
// ConvTranspose2d k=4 s=2 p=1, parity decomposition, 2 A-rows per thread,
// OCT small so acc fits. REVERTED to validated R20 (256,2): R22's (256,3)
// squeezed VGPR to 84 < live values -> scratch spill (WRITE 397MB, 735us).
// ---------------------------------------------------------------------------
template<int CIN, int COUT, int OCT, int HIN, int ICC, int ACT, bool INL>
__launch_bounds__(256, 2)
__global__ void convt_k(const float* __restrict__ in, const float* __restrict__ w,
                        const float* __restrict__ bias, float* __restrict__ out)
{
    constexpr int WIN = HIN, HOUT = 2 * HIN, WOUT = 2 * HIN;
    __shared__ float sw[ICC * 16 * OCT];
    const int tid = threadIdx.x;
    const int tx = tid & 15, ty = tid >> 4;
    constexpr int TBW = WOUT / 32;
    const int bx = blockIdx.x % TBW, by = blockIdx.x / TBW;
    const int A0 = by * 32 + ty;
    const int A1 = A0 + 16;
    const int C = bx * 16 + tx;
    const int oc0 = blockIdx.y * OCT;
    const int n = blockIdx.z;

    int offs[2][9]; float msk[2][9];
#pragma unroll
    for (int h = 0; h < 2; ++h) {
        const int A = h ? A1 : A0;
#pragma unroll
        for (int dy = 0; dy < 3; ++dy) {
#pragma unroll
            for (int dx = 0; dx < 3; ++dx) {
                const int iy = A - 1 + dy, ix = C - 1 + dx;
                const bool v = (iy >= 0) && (iy < HIN) && (ix >= 0) && (ix < WIN);
                offs[h][dy * 3 + dx] = v ? iy * WIN + ix : 0;
                msk[h][dy * 3 + dx] = v ? 1.f : 0.f;
            }
        }
    }

    float acc[2][4 * OCT];
#pragma unroll
    for (int h = 0; h < 2; ++h)
#pragma unroll
        for (int j = 0; j < 4 * OCT; ++j) acc[h][j] = 0.f;

    for (int ic0 = 0; ic0 < CIN; ic0 += ICC) {
        __syncthreads();
        for (int t = tid; t < ICC * 16 * OCT; t += 256) {
            int oc_l = t % OCT, r = t / OCT, k = r & 15, ic_l = r >> 4;
            sw[(ic_l * 16 + k) * OCT + oc_l] =
                w[((size_t)(ic0 + ic_l) * COUT + oc0 + oc_l) * 16 + k];
        }
        __syncthreads();
#pragma unroll 1
        for (int ic_l = 0; ic_l < ICC; ++ic_l) {
            const float* ip = in + (size_t)(n * CIN + ic0 + ic_l) * HIN * WIN;
            float in9[2][9];
#pragma unroll
            for (int h = 0; h < 2; ++h)
#pragma unroll
                for (int j = 0; j < 9; ++j) {
                    float v = ip[offs[h][j]] * msk[h][j];
                    if (INL) v = lrelu_in(v);
                    in9[h][j] = v;
                }
#pragma unroll
            for (int ky = 0; ky < 4; ++ky) {
                const int ry = (ky + 1) & 1;
                const int dy = 2 - ((ky + 1) >> 1);
#pragma unroll
                for (int kx = 0; kx < 4; ++kx) {
                    const int rx = (kx + 1) & 1;
                    const int dx = 2 - ((kx + 1) >> 1);
                    const float va = in9[0][dy * 3 + dx];
                    const float vb = in9[1][dy * 3 + dx];
                    const int po = ry * 2 + rx;
                    const float4* wp = (const float4*)&sw[(ic_l * 16 + ky * 4 + kx) * OCT];
#pragma unroll
                    for (int q4 = 0; q4 < OCT / 4; ++q4) {
                        float4 wv = wp[q4];
                        acc[0][po * OCT + q4 * 4 + 0] = fmaf(wv.x, va, acc[0][po * OCT + q4 * 4 + 0]);
                        acc[0][po * OCT + q4 * 4 + 1] = fmaf(wv.y, va, acc[0][po * OCT + q4 * 4 + 1]);
                        acc[0][po * OCT + q4 * 4 + 2] = fmaf(wv.z, va, acc[0][po * OCT + q4 * 4 + 2]);
                        acc[0][po * OCT + q4 * 4 + 3] = fmaf(wv.w, va, acc[0][po * OCT + q4 * 4 + 3]);
                        acc[1][po * OCT + q4 * 4 + 0] = fmaf(wv.x, vb, acc[1][po * OCT + q4 * 4 + 0]);
                        acc[1][po * OCT + q4 * 4 + 1] = fmaf(wv.y, vb, acc[1][po * OCT + q4 * 4 + 1]);
                        acc[1][po * OCT + q4 * 4 + 2] = fmaf(wv.z, vb, acc[1][po * OCT + q4 * 4 + 2]);
                        acc[1][po * OCT + q4 * 4 + 3] = fmaf(wv.w, vb, acc[1][po * OCT + q4 * 4 + 3]);
                    }
                }
            }
        }
    }
#pragma unroll
    for (int h = 0; h < 2; ++h) {
        const int A = h ? A1 : A0;
#pragma unroll
        for (int po = 0; po < 4; ++po) {
            const int ry = po >> 1, rx = po & 1;
            const int oy = 2 * A + ry, ox = 2 * C + rx;
#pragma unroll
            for (int j = 0; j < OCT; ++j) {
                float r = acc[h][po * OCT + j] + bias[oc0 + j];
                r = actf<ACT>(r);
                out[((size_t)(n * COUT + oc0 + j) * HOUT + oy) * WOUT + ox] = r;
            }
        }
    }
}

// ---------------------------------------------------------------------------
// Codebook norms, precomputed once. (validated R7/R8)
// ---------------------------------------------------------------------------
__global__ void norm_k(const float* __restrict__ cb, float* __restrict__ nrm) {
    const int c = blockIdx.x * 256 + threadIdx.x;   // 0..2047
    const float4* p = (const float4*)(cb + (size_t)c * 64);
    float a0 = 0.f, a1 = 0.f, a2 = 0.f, a3 = 0.f;
#pragma unroll
    for (int i = 0; i < 16; ++i) {
        float4 v = p[i];
        a0 = fmaf(v.x, v.x, a0); a1 = fmaf(v.y, v.y, a1);
        a2 = fmaf(v.z, v.z, a2); a3 = fmaf(v.w, v.w, a3);
    }
    nrm[c] = (a0 + a1) + (a2 + a3);
}

// ---------------------------------------------------------------------------
// Residual VQ v5 (NT=2 register blocking + 4-way code split). Validated R18:
// 402us, Occ 21.4, VALUBusy 51. NUMERICS: exact validated chains.
// ---------------------------------------------------------------------------
__launch_bounds__(256, 2)
__global__ void rvq_k(const float* __restrict__ z, const float* __restrict__ cb,
                      const float* __restrict__ nrm,
                      float* __restrict__ q, float* __restrict__ idx_out,
                      float* __restrict__ loss_acc)
{
    __shared__ float scb[256 * 64];     // 64 KB: 256 staged code rows
    __shared__ float snrm[256];
    __shared__ float lmin[4][2][64];    // [wave][token-slot][lane]
    __shared__ int   lidx[4][2][64];
    const int tid = threadIdx.x;
    const int lane = tid & 63;
    const int w = __builtin_amdgcn_readfirstlane(tid >> 6);   // wave id 0..3
    const int t0 = blockIdx.x * 128 + lane;                    // slot-0 token
    const int t1 = t0 + 64;                                    // slot-1 token

    float r0[64], r1[64];
    {
        const float4* zp0 = (const float4*)(z + (size_t)t0 * 64);
        const float4* zp1 = (const float4*)(z + (size_t)t1 * 64);
#pragma unroll
        for (int i = 0; i < 16; ++i) {
            float4 v = zp0[i];
            r0[4 * i + 0] = v.x; r0[4 * i + 1] = v.y;
            r0[4 * i + 2] = v.z; r0[4 * i + 3] = v.w;
            float4 u = zp1[i];
            r1[4 * i + 0] = u.x; r1[4 * i + 1] = u.y;
            r1[4 * i + 2] = u.z; r1[4 * i + 3] = u.w;
        }
    }

    for (int s = 0; s < 4; ++s) {
        float sr20, sr21;
        {
            float a0 = 0.f, a1 = 0.f, a2 = 0.f, a3 = 0.f;
            float b0 = 0.f, b1 = 0.f, b2 = 0.f, b3 = 0.f;
#pragma unroll
            for (int i = 0; i < 32; i += 4) {
                a0 = fmaf(r0[i + 0], r0[i + 0], a0);
                a1 = fmaf(r0[i + 1], r0[i + 1], a1);
                a2 = fmaf(r0[i + 2], r0[i + 2], a2);
                a3 = fmaf(r0[i + 3], r0[i + 3], a3);
                b0 = fmaf(r0[32 + i + 0], r0[32 + i + 0], b0);
                b1 = fmaf(r0[32 + i + 1], r0[32 + i + 1], b1);
                b2 = fmaf(r0[32 + i + 2], r0[32 + i + 2], b2);
                b3 = fmaf(r0[32 + i + 3], r0[32 + i + 3], b3);
            }
            sr20 = ((a0 + a1) + (a2 + a3)) + ((b0 + b1) + (b2 + b3));
        }
        {
            float a0 = 0.f, a1 = 0.f, a2 = 0.f, a3 = 0.f;
            float b0 = 0.f, b1 = 0.f, b2 = 0.f, b3 = 0.f;
#pragma unroll
            for (int i = 0; i < 32; i += 4) {
                a0 = fmaf(r1[i + 0], r1[i + 0], a0);
                a1 = fmaf(r1[i + 1], r1[i + 1], a1);
                a2 = fmaf(r1[i + 2], r1[i + 2], a2);
                a3 = fmaf(r1[i + 3], r1[i + 3], a3);
                b0 = fmaf(r1[32 + i + 0], r1[32 + i + 0], b0);
                b1 = fmaf(r1[32 + i + 1], r1[32 + i + 1], b1);
                b2 = fmaf(r1[32 + i + 2], r1[32 + i + 2], b2);
                b3 = fmaf(r1[32 + i + 3], r1[32 + i + 3], b3);
            }
            sr21 = ((a0 + a1) + (a2 + a3)) + ((b0 + b1) + (b2 + b3));
        }

        float dmin0 = 3.4e38f, dmin1 = 3.4e38f;
        int best0 = 0, best1 = 0;

        for (int pass = 0; pass < 2; ++pass) {
            __syncthreads();
            {
                const float4* csrc = (const float4*)(cb + (size_t)s * 512 * 64);
                for (int i = tid; i < 4096; i += 256) {
                    const int row = i >> 4, f4 = i & 15;
                    const int grow = (row >> 6) * 128 + pass * 64 + (row & 63);
                    ((float4*)scb)[row * 16 + f4] = csrc[(size_t)grow * 16 + f4];
                }
                const int g = (tid >> 6) * 128 + pass * 64 + (tid & 63);
                snrm[tid] = nrm[s * 512 + g];
            }
            __syncthreads();

#pragma unroll 2
            for (int kk = 0; kk < 64; ++kk) {
                const float4* cp = (const float4*)&scb[(size_t)(w * 64 + kk) * 64];
                float a0 = 0.f, a1 = 0.f, a2 = 0.f, a3 = 0.f;
                float e0 = 0.f, e1 = 0.f, e2 = 0.f, e3 = 0.f;
#pragma unroll
                for (int i = 0; i < 8; ++i) {
                    float4 c = cp[i];
                    a0 = fmaf(r0[4 * i + 0], c.x, a0);
                    a1 = fmaf(r0[4 * i + 1], c.y, a1);
                    a2 = fmaf(r0[4 * i + 2], c.z, a2);
                    a3 = fmaf(r0[4 * i + 3], c.w, a3);
                    e0 = fmaf(r1[4 * i + 0], c.x, e0);
                    e1 = fmaf(r1[4 * i + 1], c.y, e1);
                    e2 = fmaf(r1[4 * i + 2], c.z, e2);
                    e3 = fmaf(r1[4 * i + 3], c.w, e3);
                }
                float b0 = 0.f, b1 = 0.f, b2 = 0.f, b3 = 0.f;
                float f0 = 0.f, f1 = 0.f, f2 = 0.f, f3 = 0.f;
#pragma unroll
                for (int i = 0; i < 8; ++i) {
                    float4 c = cp[8 + i];
                    b0 = fmaf(r0[32 + 4 * i + 0], c.x, b0);
                    b1 = fmaf(r0[32 + 4 * i + 1], c.y, b1);
                    b2 = fmaf(r0[32 + 4 * i + 2], c.z, b2);
                    b3 = fmaf(r0[32 + 4 * i + 3], c.w, b3);
                    f0 = fmaf(r1[32 + 4 * i + 0], c.x, f0);
                    f1 = fmaf(r1[32 + 4 * i + 1], c.y, f1);
                    f2 = fmaf(r1[32 + 4 * i + 2], c.z, f2);
                    f3 = fmaf(r1[32 + 4 * i + 3], c.w, f3);
                }
                const float dot0 = ((a0 + a1) + (a2 + a3)) + ((b0 + b1) + (b2 + b3));
                const float dot1 = ((e0 + e1) + (e2 + e3)) + ((f0 + f1) + (f2 + f3));
                const float nk = snrm[w * 64 + kk];
                const float d0 = fmaf(-2.f, dot0, sr20) + nk;
                const float d1 = fmaf(-2.f, dot1, sr21) + nk;
                const int kl = pass * 64 + kk;
                if (d0 < dmin0) { dmin0 = d0; best0 = kl; }
                if (d1 < dmin1) { dmin1 = d1; best1 = kl; }
            }
        }

        lmin[w][0][lane] = dmin0; lidx[w][0][lane] = best0 + w * 128;
        lmin[w][1][lane] = dmin1; lidx[w][1][lane] = best1 + w * 128;
        __syncthreads();
        float d0c = lmin[0][0][lane]; int b0c = lidx[0][0][lane];
        float d1c = lmin[0][1][lane]; int b1c = lidx[0][1][lane];
#pragma unroll
        for (int ww = 1; ww < 4; ++ww) {
            const float dd0 = lmin[ww][0][lane]; const int ii0 = lidx[ww][0][lane];
            if (dd0 < d0c) { d0c = dd0; b0c = ii0; }
            const float dd1 = lmin[ww][1][lane]; const int ii1 = lidx[ww][1][lane];
            if (dd1 < d1c) { d1c = dd1; b1c = ii1; }
        }

        if (w < 2) {
            float lv = (w == 0) ? d0c : d1c;
#pragma unroll
            for (int off = 32; off; off >>= 1) lv += __shfl_down(lv, off, 64);
            if (lane == 0) atomicAdd(&loss_acc[s], lv);
        }
        if (w == 0)      idx_out[(size_t)t0 * 4 + s] = (float)b0c;
        else if (w == 1) idx_out[(size_t)t1 * 4 + s] = (float)b1c;

        const float4* c0 = (const float4*)(cb + ((size_t)s * 512 + b0c) * 64);
        const float4* c1 = (const float4*)(cb + ((size_t)s * 512 + b1c) * 64);
#pragma unroll
        for (int i = 0; i < 16; ++i) {
            float4 v = c0[i];
            r0[4 * i + 0] -= v.x; r0[4 * i + 1] -= v.y;
            r0[4 * i + 2] -= v.z; r0[4 * i + 3] -= v.w;
            float4 u = c1[i];
            r1[4 * i + 0] -= u.x; r1[4 * i + 1] -= u.y;
            r1[4 * i + 2] -= u.z; r1[4 * i + 3] -= u.w;
        }
    }

    if (w == 0) {
        const float4* zp = (const float4*)(z + (size_t)t0 * 64);
        const int n = t0 >> 12, pix = t0 & 4095;
        float* qp = q + (size_t)n * 64 * 4096 + pix;
#pragma unroll
        for (int i = 0; i < 16; ++i) {
            float4 v = zp[i];
            qp[(size_t)(4 * i + 0) * 4096] = v.x - r0[4 * i + 0];
            qp[(size_t)(4 * i + 1) * 4096] = v.y - r0[4 * i + 1];
            qp[(size_t)(4 * i + 2) * 4096] = v.z - r0[4 * i + 2];
            qp[(size_t)(4 * i + 3) * 4096] = v.w - r0[4 * i + 3];
        }
    } else if (w == 1) {
        const float4* zp = (const float4*)(z + (size_t)t1 * 64);
        const int n = t1 >> 12, pix = t1 & 4095;
        float* qp = q + (size_t)n * 64 * 4096 + pix;
#pragma unroll
        for (int i = 0; i < 16; ++i) {
            float4 v = zp[i];
            qp[(size_t)(4 * i + 0) * 4096] = v.x - r1[4 * i + 0];
            qp[(size_t)(4 * i + 1) * 4096] = v.y - r1[4 * i + 1];
            qp[(size_t)(4 * i + 2) * 4096] = v.z - r1[4 * i + 2];
            qp[(size_t)(4 * i + 3) * 4096] = v.w - r1[4 * i + 3];
        }
    }
}

__global__ void init_k(float* loss_acc) {
    if (threadIdx.x < 4) loss_acc[threadIdx.x] = 0.f;
}
__global__ void fin_k(const float* __restrict__ loss_acc, float* __restrict__ out_loss) {
    if (threadIdx.x < 4)
        out_loss[threadIdx.x] = loss_acc[threadIdx.x] * (0.25f / 4194304.f); // BETA/(N*D)
}

// ---------------------------------------------------------------------------
extern "C" void kernel_launch(void* const* d_in, const int* in_sizes, int n_in,
                              void* d_out, int out_size, void* d_ws, size_t ws_size,
                              hipStream_t stream)
{
    const float* x    = (const float*)d_in[0];
    const float* e1w  = (const float*)d_in[1];  const float* e1b = (const float*)d_in[2];
    const float* e2w  = (const float*)d_in[3];  const float* e2b = (const float*)d_in[4];
    const float* e3w  = (const float*)d_in[5];  const float* e3b = (const float*)d_in[6];
    const float* r1aw = (const float*)d_in[7];  const float* r1bw = (const float*)d_in[8];
    const float* r2aw = (const float*)d_in[9];  const float* r2bw = (const float*)d_in[10];
    const float* e4w  = (const float*)d_in[11]; const float* e4b = (const float*)d_in[12];
    const float* cbs  = (const float*)d_in[13];
    const float* d1w  = (const float*)d_in[14]; const float* d1b = (const float*)d_in[15];
    const float* dr1aw= (const float*)d_in[16]; const float* dr1bw = (const float*)d_in[17];
    const float* dr2aw= (const float*)d_in[18]; const float* dr2bw = (const float*)d_in[19];
    const float* dt1w = (const float*)d_in[20]; const float* dt1b = (const float*)d_in[21];
    const float* dt2w = (const float*)d_in[22]; const float* dt2b = (const float*)d_in[23];

    float* out = (float*)d_out;
    float* ws  = (float*)d_ws;

    float* BIG = ws;                    // 16.78M floats (e1 out / dt1 out)
    float* P2  = BIG;
    float* P3  = BIG + 8388608;
    float* P1  = ws + 16777216;
    float* Z   = ws + 25165824;
    float* Q   = ws + 29360128;
    float* LACC= ws + 33554432;         // 4 floats
    float* NRM = ws + 33554448;         // 2048 floats

    float* out_recons = out;                    // 16*4*256*256 = 4194304
    float* out_idx    = out + 4194304;          // 16*64*64*4   = 262144
    float* out_loss   = out + 4194304 + 262144; // 4

    init_k<<<1, 64, 0, stream>>>(LACC);
    norm_k<<<8, 256, 0, stream>>>(cbs, NRM);

    // ---- encoder ----
    conv_k<4, 64, 4, 2, 1, 256, 256, 128, 128, 4, 2, 2, true>
        <<<dim3(32, 4, 16), 256, 0, stream>>>(x, e1w, e1b, BIG);
    // e2: NPY=4, OCT=8, 3 blocks/CU (R22, spill-safe acc=32)
    conv_oct_k<64, 128, 4, 2, 1, 128, 128, 64, 64, 16, 4, 8, 3, 2, true>
        <<<dim3(4, 16, 16), 256, 0, stream>>>(BIG, e2w, e2b, P1);
    conv3_k<128, 128, 16, 2, true>
        <<<dim3(2, 16, 16), 256, 0, stream>>>(P1, e3w, e3b, P2);
    conv3_k<128, 128, 16, 1, false>
        <<<dim3(2, 16, 16), 256, 0, stream>>>(P2, r1aw, nullptr, P3);
    conv1x1_k<128, 128, 4, 0, false, false, true, false>
        <<<dim3(4, 8, 16), 256, 0, stream>>>(P3, r1bw, nullptr, P2, P1);
    conv3_k<128, 128, 16, 1, false>
        <<<dim3(2, 16, 16), 256, 0, stream>>>(P1, r2aw, nullptr, P3);
    conv1x1_k<128, 128, 4, 0, false, false, true, false>
        <<<dim3(4, 8, 16), 256, 0, stream>>>(P3, r2bw, nullptr, P1, P2);
    conv1x1_k<128, 64, 2, 2, true, true, false, true>
        <<<dim3(8, 4, 16), 256, 0, stream>>>(P2, e4w, e4b, nullptr, Z);

    // ---- residual VQ ----
    rvq_k<<<512, 256, 0, stream>>>(Z, cbs, NRM, Q, out_idx, LACC);
    fin_k<<<1, 64, 0, stream>>>(LACC, out_loss);

    // ---- decoder ----
    conv3_k<64, 128, 16, 2, true>
        <<<dim3(2, 16, 16), 256, 0, stream>>>(Q, d1w, d1b, P1);
    conv3_k<128, 128, 16, 1, false>
        <<<dim3(2, 16, 16), 256, 0, stream>>>(P1, dr1aw, nullptr, P2);
    conv1x1_k<128, 128, 4, 0, false, false, true, false>
        <<<dim3(4, 8, 16), 256, 0, stream>>>(P2, dr1bw, nullptr, P1, P3);
    conv3_k<128, 128, 16, 1, false>
        <<<dim3(2, 16, 16), 256, 0, stream>>>(P3, dr2aw, nullptr, P2);
    conv1x1_k<128, 128, 4, 0, false, false, true, false>
        <<<dim3(4, 8, 16), 256, 0, stream>>>(P2, dr2bw, nullptr, P3, P1);
    // dt1: OCT=8, 2 A-rows/thread -> grid (TBW=4 x 2 A-tiles = 8, 64/8 = 8, 16)
    convt_k<128, 64, 8, 64, 8, 2, true>
        <<<dim3(8, 8, 16), 256, 0, stream>>>(P1, dt1w, dt1b, BIG);
    // dt2: OCT=4 -> grid (TBW=8 x 4 A-tiles = 32, 1, 16)
    convt_k<64, 4, 4, 128, 16, 1, false>
        <<<dim3(32, 1, 16), 256, 0, stream>>>(BIG, dt2w, dt2b, out_recons);
}

// Round 11
// 2704.756 us; speedup vs baseline: 1.1714x; 1.0331x over previous
//
#include <hip/hip_runtime.h>
#include <cstddef>

// ---------------------------------------------------------------------------
// RQ-VAE forward on MI355X. Round 24: restore the best-measured config (R20,
// 2706us) exactly. Ledger: R20=2706 (e2 conv_k NPY=2, 3x3 conv_k, convt
// OCT=8 (256,2)); R21 conv3_k=2726 (noise); R22 convt(256,3)=3168 (spill);
// R23 e2 conv_oct=2794 (regression -- occupancy didn't pay on the strided
// layer; R12 history was right). All conv variants plateau at VALUBusy
// 40-50% / Occ ~21% for FP32 direct conv; remaining lever (bf16 MFMA) risks
// index numerics (R14). Locking the best-known kernel.
// ---------------------------------------------------------------------------

template<int ACT> __device__ __forceinline__ float actf(float v) {
    if constexpr (ACT == 1) return v > 0.f ? v : 0.f;            // relu
    else if constexpr (ACT == 2) return v > 0.f ? v : 0.01f * v; // leaky relu
    else return v;
}
__device__ __forceinline__ float lrelu_in(float v) { return v > 0.f ? v : 0.01f * v; }

// ---------------------------------------------------------------------------
// Direct conv: thread = NPY vertical output pixels x 16 output channels.
// (validated R8; used for e1, e2, and the six 3x3 s1 layers)
// ---------------------------------------------------------------------------
template<int CIN, int COUT, int K, int S, int P, int HIN, int WIN, int HOUT, int WOUT,
         int ICC, int NPY, int ACT, bool BIAS>
__launch_bounds__(256, (NPY >= 4 ? 2 : 4))
__global__ void conv_k(const float* __restrict__ in, const float* __restrict__ w,
                       const float* __restrict__ bias, float* __restrict__ out)
{
    constexpr int K2 = K * K;
    constexpr int NR = S * (NPY - 1) + K;
    constexpr int BH = 16 * NPY;
    __shared__ float sw[ICC * K2 * 16];
    const int tid = threadIdx.x;
    const int tx = tid & 15, ty = tid >> 4;
    constexpr int TW = WOUT / 16;
    const int bx = blockIdx.x % TW, by = blockIdx.x / TW;
    const int ox = bx * 16 + tx;
    const int oy0 = by * BH + ty * NPY;
    const int oc0 = blockIdx.y * 16;
    const int n = blockIdx.z;
    const int ix0 = ox * S - P, iy0 = oy0 * S - P;

    int ro[NR]; float mr[NR];
#pragma unroll
    for (int r = 0; r < NR; ++r) {
        const int iy = iy0 + r;
        const bool v = (iy >= 0) && (iy < HIN);
        ro[r] = v ? iy * WIN : 0;
        mr[r] = v ? 1.f : 0.f;
    }
    int co[K]; float mc[K];
#pragma unroll
    for (int c = 0; c < K; ++c) {
        const int ix = ix0 + c;
        const bool v = (ix >= 0) && (ix < WIN);
        co[c] = v ? ix : 0;
        mc[c] = v ? 1.f : 0.f;
    }

    float acc[NPY][16];
#pragma unroll
    for (int py = 0; py < NPY; ++py)
#pragma unroll
        for (int j = 0; j < 16; ++j) acc[py][j] = 0.f;

    for (int ic0 = 0; ic0 < CIN; ic0 += ICC) {
        __syncthreads();
        for (int t = tid; t < ICC * K2 * 16; t += 256) {
            int oc_l = t & 15, r = t >> 4, k = r % K2, ic_l = r / K2;
            sw[(ic_l * K2 + k) * 16 + oc_l] =
                w[((size_t)(oc0 + oc_l) * CIN + ic0 + ic_l) * K2 + k];
        }
        __syncthreads();
#pragma unroll 1
        for (int ic_l = 0; ic_l < ICC; ++ic_l) {
            const float* ip = in + (size_t)(n * CIN + ic0 + ic_l) * HIN * WIN;
            float patch[NR][K];
#pragma unroll
            for (int r = 0; r < NR; ++r)
#pragma unroll
                for (int c = 0; c < K; ++c)
                    patch[r][c] = ip[ro[r] + co[c]] * (mr[r] * mc[c]);
            const float* swp = &sw[ic_l * K2 * 16];
#pragma unroll
            for (int ky = 0; ky < K; ++ky) {
#pragma unroll
                for (int kx = 0; kx < K; ++kx) {
                    const float4* wp = (const float4*)&swp[(ky * K + kx) * 16];
                    float4 w0 = wp[0], w1 = wp[1], w2 = wp[2], w3 = wp[3];
#pragma unroll
                    for (int py = 0; py < NPY; ++py) {
                        const float v = patch[py * S + ky][kx];
                        acc[py][0]  = fmaf(w0.x, v, acc[py][0]);
                        acc[py][1]  = fmaf(w0.y, v, acc[py][1]);
                        acc[py][2]  = fmaf(w0.z, v, acc[py][2]);
                        acc[py][3]  = fmaf(w0.w, v, acc[py][3]);
                        acc[py][4]  = fmaf(w1.x, v, acc[py][4]);
                        acc[py][5]  = fmaf(w1.y, v, acc[py][5]);
                        acc[py][6]  = fmaf(w1.z, v, acc[py][6]);
                        acc[py][7]  = fmaf(w1.w, v, acc[py][7]);
                        acc[py][8]  = fmaf(w2.x, v, acc[py][8]);
                        acc[py][9]  = fmaf(w2.y, v, acc[py][9]);
                        acc[py][10] = fmaf(w2.z, v, acc[py][10]);
                        acc[py][11] = fmaf(w2.w, v, acc[py][11]);
                        acc[py][12] = fmaf(w3.x, v, acc[py][12]);
                        acc[py][13] = fmaf(w3.y, v, acc[py][13]);
                        acc[py][14] = fmaf(w3.z, v, acc[py][14]);
                        acc[py][15] = fmaf(w3.w, v, acc[py][15]);
                    }
                }
            }
        }
    }
#pragma unroll
    for (int py = 0; py < NPY; ++py) {
#pragma unroll
        for (int j = 0; j < 16; ++j) {
            float r = acc[py][j];
            if (BIAS) r += bias[oc0 + j];
            r = actf<ACT>(r);
            out[((size_t)(n * COUT + oc0 + j) * HOUT + oy0 + py) * WOUT + ox] = r;
        }
    }
}

// ---------------------------------------------------------------------------
// 1x1 conv over 64x64 maps (HW=4096), NPX pixels per thread. (validated R8)
// ---------------------------------------------------------------------------
template<int CIN, int COUT, int NPX, int ACT, bool BIAS, bool INL, bool RESID, bool TOK>
__launch_bounds__(256, 3)
__global__ void conv1x1_k(const float* __restrict__ in, const float* __restrict__ w,
                          const float* __restrict__ bias, const float* __restrict__ resid,
                          float* __restrict__ out)
{
    constexpr int HW = 4096;
    __shared__ float sw[16 * CIN];
    const int tid = threadIdx.x;
    const int base = blockIdx.x * (256 * NPX) + tid;
    const int oc0 = blockIdx.y * 16;
    const int n = blockIdx.z;

    for (int t = tid; t < 16 * CIN; t += 256) {
        int oc_l = t & 15, ic = t >> 4;
        sw[ic * 16 + oc_l] = w[(size_t)(oc0 + oc_l) * CIN + ic];
    }
    __syncthreads();

    float acc[NPX][16];
#pragma unroll
    for (int p = 0; p < NPX; ++p)
#pragma unroll
        for (int j = 0; j < 16; ++j) acc[p][j] = 0.f;

    const float* ip = in + (size_t)n * CIN * HW;
#pragma unroll 2
    for (int ic = 0; ic < CIN; ++ic) {
        float v[NPX];
#pragma unroll
        for (int p = 0; p < NPX; ++p) {
            float t = ip[(size_t)ic * HW + base + 256 * p];
            if (INL) t = lrelu_in(t);
            v[p] = t;
        }
        const float4* wp = (const float4*)&sw[ic * 16];
#pragma unroll
        for (int q4 = 0; q4 < 4; ++q4) {
            const float4 wv = wp[q4];
#pragma unroll
            for (int p = 0; p < NPX; ++p) {
                acc[p][q4 * 4 + 0] = fmaf(wv.x, v[p], acc[p][q4 * 4 + 0]);
                acc[p][q4 * 4 + 1] = fmaf(wv.y, v[p], acc[p][q4 * 4 + 1]);
                acc[p][q4 * 4 + 2] = fmaf(wv.z, v[p], acc[p][q4 * 4 + 2]);
                acc[p][q4 * 4 + 3] = fmaf(wv.w, v[p], acc[p][q4 * 4 + 3]);
            }
        }
    }
#pragma unroll
    for (int p = 0; p < NPX; ++p) {
        const int pix = base + 256 * p;
#pragma unroll
        for (int j = 0; j < 16; ++j) {
            float r = acc[p][j];
            if (BIAS) r += bias[oc0 + j];
            r = actf<ACT>(r);
            if (RESID) r += resid[((size_t)(n * COUT + oc0 + j)) * HW + pix];
            if (TOK)
                out[((size_t)n * HW + pix) * COUT + oc0 + j] = r;
            else
                out[((size_t)(n * COUT + oc0 + j)) * HW + pix] = r;
        }
    }
}

// ---------------------------------------------------------------------------
// ConvTranspose2d k=4 s=2 p=1, parity decomposition, 2 A-rows per thread,
// OCT small so acc fits, launch_bounds(256,2). (validated R20; R22's (256,3)
// squeezed VGPR to 84 < live values -> scratch spill -- never again)
// ---------------------------------------------------------------------------
template<int CIN, int COUT, int OCT, int HIN, int ICC, int ACT, bool INL>
__launch_bounds__(256, 2)
__global__ void convt_k(const float* __restrict__ in, const float* __restrict__ w,
                        const float* __restrict__ bias, float* __restrict__ out)
{
    constexpr int WIN = HIN, HOUT = 2 * HIN, WOUT = 2 * HIN;
    __shared__ float sw[ICC * 16 * OCT];
    const int tid = threadIdx.x;
    const int tx = tid & 15, ty = tid >> 4;
    constexpr int TBW = WOUT / 32;
    const int bx = blockIdx.x % TBW, by = blockIdx.x / TBW;
    const int A0 = by * 32 + ty;
    const int A1 = A0 + 16;
    const int C = bx * 16 + tx;
    const int oc0 = blockIdx.y * OCT;
    const int n = blockIdx.z;

    int offs[2][9]; float msk[2][9];
#pragma unroll
    for (int h = 0; h < 2; ++h) {
        const int A = h ? A1 : A0;
#pragma unroll
        for (int dy = 0; dy < 3; ++dy) {
#pragma unroll
            for (int dx = 0; dx < 3; ++dx) {
                const int iy = A - 1 + dy, ix = C - 1 + dx;
                const bool v = (iy >= 0) && (iy < HIN) && (ix >= 0) && (ix < WIN);
                offs[h][dy * 3 + dx] = v ? iy * WIN + ix : 0;
                msk[h][dy * 3 + dx] = v ? 1.f : 0.f;
            }
        }
    }

    float acc[2][4 * OCT];
#pragma unroll
    for (int h = 0; h < 2; ++h)
#pragma unroll
        for (int j = 0; j < 4 * OCT; ++j) acc[h][j] = 0.f;

    for (int ic0 = 0; ic0 < CIN; ic0 += ICC) {
        __syncthreads();
        for (int t = tid; t < ICC * 16 * OCT; t += 256) {
            int oc_l = t % OCT, r = t / OCT, k = r & 15, ic_l = r >> 4;
            sw[(ic_l * 16 + k) * OCT + oc_l] =
                w[((size_t)(ic0 + ic_l) * COUT + oc0 + oc_l) * 16 + k];
        }
        __syncthreads();
#pragma unroll 1
        for (int ic_l = 0; ic_l < ICC; ++ic_l) {
            const float* ip = in + (size_t)(n * CIN + ic0 + ic_l) * HIN * WIN;
            float in9[2][9];
#pragma unroll
            for (int h = 0; h < 2; ++h)
#pragma unroll
                for (int j = 0; j < 9; ++j) {
                    float v = ip[offs[h][j]] * msk[h][j];
                    if (INL) v = lrelu_in(v);
                    in9[h][j] = v;
                }
#pragma unroll
            for (int ky = 0; ky < 4; ++ky) {
                const int ry = (ky + 1) & 1;
                const int dy = 2 - ((ky + 1) >> 1);
#pragma unroll
                for (int kx = 0; kx < 4; ++kx) {
                    const int rx = (kx + 1) & 1;
                    const int dx = 2 - ((kx + 1) >> 1);
                    const float va = in9[0][dy * 3 + dx];
                    const float vb = in9[1][dy * 3 + dx];
                    const int po = ry * 2 + rx;
                    const float4* wp = (const float4*)&sw[(ic_l * 16 + ky * 4 + kx) * OCT];
#pragma unroll
                    for (int q4 = 0; q4 < OCT / 4; ++q4) {
                        float4 wv = wp[q4];
                        acc[0][po * OCT + q4 * 4 + 0] = fmaf(wv.x, va, acc[0][po * OCT + q4 * 4 + 0]);
                        acc[0][po * OCT + q4 * 4 + 1] = fmaf(wv.y, va, acc[0][po * OCT + q4 * 4 + 1]);
                        acc[0][po * OCT + q4 * 4 + 2] = fmaf(wv.z, va, acc[0][po * OCT + q4 * 4 + 2]);
                        acc[0][po * OCT + q4 * 4 + 3] = fmaf(wv.w, va, acc[0][po * OCT + q4 * 4 + 3]);
                        acc[1][po * OCT + q4 * 4 + 0] = fmaf(wv.x, vb, acc[1][po * OCT + q4 * 4 + 0]);
                        acc[1][po * OCT + q4 * 4 + 1] = fmaf(wv.y, vb, acc[1][po * OCT + q4 * 4 + 1]);
                        acc[1][po * OCT + q4 * 4 + 2] = fmaf(wv.z, vb, acc[1][po * OCT + q4 * 4 + 2]);
                        acc[1][po * OCT + q4 * 4 + 3] = fmaf(wv.w, vb, acc[1][po * OCT + q4 * 4 + 3]);
                    }
                }
            }
        }
    }
#pragma unroll
    for (int h = 0; h < 2; ++h) {
        const int A = h ? A1 : A0;
#pragma unroll
        for (int po = 0; po < 4; ++po) {
            const int ry = po >> 1, rx = po & 1;
            const int oy = 2 * A + ry, ox = 2 * C + rx;
#pragma unroll
            for (int j = 0; j < OCT; ++j) {
                float r = acc[h][po * OCT + j] + bias[oc0 + j];
                r = actf<ACT>(r);
                out[((size_t)(n * COUT + oc0 + j) * HOUT + oy) * WOUT + ox] = r;
            }
        }
    }
}

// ---------------------------------------------------------------------------
// Codebook norms, precomputed once. (validated R7/R8)
// ---------------------------------------------------------------------------
__global__ void norm_k(const float* __restrict__ cb, float* __restrict__ nrm) {
    const int c = blockIdx.x * 256 + threadIdx.x;   // 0..2047
    const float4* p = (const float4*)(cb + (size_t)c * 64);
    float a0 = 0.f, a1 = 0.f, a2 = 0.f, a3 = 0.f;
#pragma unroll
    for (int i = 0; i < 16; ++i) {
        float4 v = p[i];
        a0 = fmaf(v.x, v.x, a0); a1 = fmaf(v.y, v.y, a1);
        a2 = fmaf(v.z, v.z, a2); a3 = fmaf(v.w, v.w, a3);
    }
    nrm[c] = (a0 + a1) + (a2 + a3);
}

// ---------------------------------------------------------------------------
// Residual VQ v5 (NT=2 register blocking + 4-way code split). Validated R18:
// 402us, Occ 21.4, VALUBusy 51. NUMERICS: exact validated chains.
// ---------------------------------------------------------------------------
__launch_bounds__(256, 2)
__global__ void rvq_k(const float* __restrict__ z, const float* __restrict__ cb,
                      const float* __restrict__ nrm,
                      float* __restrict__ q, float* __restrict__ idx_out,
                      float* __restrict__ loss_acc)
{
    __shared__ float scb[256 * 64];     // 64 KB: 256 staged code rows
    __shared__ float snrm[256];
    __shared__ float lmin[4][2][64];    // [wave][token-slot][lane]
    __shared__ int   lidx[4][2][64];
    const int tid = threadIdx.x;
    const int lane = tid & 63;
    const int w = __builtin_amdgcn_readfirstlane(tid >> 6);   // wave id 0..3
    const int t0 = blockIdx.x * 128 + lane;                    // slot-0 token
    const int t1 = t0 + 64;                                    // slot-1 token

    float r0[64], r1[64];
    {
        const float4* zp0 = (const float4*)(z + (size_t)t0 * 64);
        const float4* zp1 = (const float4*)(z + (size_t)t1 * 64);
#pragma unroll
        for (int i = 0; i < 16; ++i) {
            float4 v = zp0[i];
            r0[4 * i + 0] = v.x; r0[4 * i + 1] = v.y;
            r0[4 * i + 2] = v.z; r0[4 * i + 3] = v.w;
            float4 u = zp1[i];
            r1[4 * i + 0] = u.x; r1[4 * i + 1] = u.y;
            r1[4 * i + 2] = u.z; r1[4 * i + 3] = u.w;
        }
    }

    for (int s = 0; s < 4; ++s) {
        float sr20, sr21;
        {
            float a0 = 0.f, a1 = 0.f, a2 = 0.f, a3 = 0.f;
            float b0 = 0.f, b1 = 0.f, b2 = 0.f, b3 = 0.f;
#pragma unroll
            for (int i = 0; i < 32; i += 4) {
                a0 = fmaf(r0[i + 0], r0[i + 0], a0);
                a1 = fmaf(r0[i + 1], r0[i + 1], a1);
                a2 = fmaf(r0[i + 2], r0[i + 2], a2);
                a3 = fmaf(r0[i + 3], r0[i + 3], a3);
                b0 = fmaf(r0[32 + i + 0], r0[32 + i + 0], b0);
                b1 = fmaf(r0[32 + i + 1], r0[32 + i + 1], b1);
                b2 = fmaf(r0[32 + i + 2], r0[32 + i + 2], b2);
                b3 = fmaf(r0[32 + i + 3], r0[32 + i + 3], b3);
            }
            sr20 = ((a0 + a1) + (a2 + a3)) + ((b0 + b1) + (b2 + b3));
        }
        {
            float a0 = 0.f, a1 = 0.f, a2 = 0.f, a3 = 0.f;
            float b0 = 0.f, b1 = 0.f, b2 = 0.f, b3 = 0.f;
#pragma unroll
            for (int i = 0; i < 32; i += 4) {
                a0 = fmaf(r1[i + 0], r1[i + 0], a0);
                a1 = fmaf(r1[i + 1], r1[i + 1], a1);
                a2 = fmaf(r1[i + 2], r1[i + 2], a2);
                a3 = fmaf(r1[i + 3], r1[i + 3], a3);
                b0 = fmaf(r1[32 + i + 0], r1[32 + i + 0], b0);
                b1 = fmaf(r1[32 + i + 1], r1[32 + i + 1], b1);
                b2 = fmaf(r1[32 + i + 2], r1[32 + i + 2], b2);
                b3 = fmaf(r1[32 + i + 3], r1[32 + i + 3], b3);
            }
            sr21 = ((a0 + a1) + (a2 + a3)) + ((b0 + b1) + (b2 + b3));
        }

        float dmin0 = 3.4e38f, dmin1 = 3.4e38f;
        int best0 = 0, best1 = 0;

        for (int pass = 0; pass < 2; ++pass) {
            __syncthreads();
            {
                const float4* csrc = (const float4*)(cb + (size_t)s * 512 * 64);
                for (int i = tid; i < 4096; i += 256) {
                    const int row = i >> 4, f4 = i & 15;
                    const int grow = (row >> 6) * 128 + pass * 64 + (row & 63);
                    ((float4*)scb)[row * 16 + f4] = csrc[(size_t)grow * 16 + f4];
                }
                const int g = (tid >> 6) * 128 + pass * 64 + (tid & 63);
                snrm[tid] = nrm[s * 512 + g];
            }
            __syncthreads();

#pragma unroll 2
            for (int kk = 0; kk < 64; ++kk) {
                const float4* cp = (const float4*)&scb[(size_t)(w * 64 + kk) * 64];
                float a0 = 0.f, a1 = 0.f, a2 = 0.f, a3 = 0.f;
                float e0 = 0.f, e1 = 0.f, e2 = 0.f, e3 = 0.f;
#pragma unroll
                for (int i = 0; i < 8; ++i) {
                    float4 c = cp[i];
                    a0 = fmaf(r0[4 * i + 0], c.x, a0);
                    a1 = fmaf(r0[4 * i + 1], c.y, a1);
                    a2 = fmaf(r0[4 * i + 2], c.z, a2);
                    a3 = fmaf(r0[4 * i + 3], c.w, a3);
                    e0 = fmaf(r1[4 * i + 0], c.x, e0);
                    e1 = fmaf(r1[4 * i + 1], c.y, e1);
                    e2 = fmaf(r1[4 * i + 2], c.z, e2);
                    e3 = fmaf(r1[4 * i + 3], c.w, e3);
                }
                float b0 = 0.f, b1 = 0.f, b2 = 0.f, b3 = 0.f;
                float f0 = 0.f, f1 = 0.f, f2 = 0.f, f3 = 0.f;
#pragma unroll
                for (int i = 0; i < 8; ++i) {
                    float4 c = cp[8 + i];
                    b0 = fmaf(r0[32 + 4 * i + 0], c.x, b0);
                    b1 = fmaf(r0[32 + 4 * i + 1], c.y, b1);
                    b2 = fmaf(r0[32 + 4 * i + 2], c.z, b2);
                    b3 = fmaf(r0[32 + 4 * i + 3], c.w, b3);
                    f0 = fmaf(r1[32 + 4 * i + 0], c.x, f0);
                    f1 = fmaf(r1[32 + 4 * i + 1], c.y, f1);
                    f2 = fmaf(r1[32 + 4 * i + 2], c.z, f2);
                    f3 = fmaf(r1[32 + 4 * i + 3], c.w, f3);
                }
                const float dot0 = ((a0 + a1) + (a2 + a3)) + ((b0 + b1) + (b2 + b3));
                const float dot1 = ((e0 + e1) + (e2 + e3)) + ((f0 + f1) + (f2 + f3));
                const float nk = snrm[w * 64 + kk];
                const float d0 = fmaf(-2.f, dot0, sr20) + nk;
                const float d1 = fmaf(-2.f, dot1, sr21) + nk;
                const int kl = pass * 64 + kk;
                if (d0 < dmin0) { dmin0 = d0; best0 = kl; }
                if (d1 < dmin1) { dmin1 = d1; best1 = kl; }
            }
        }

        lmin[w][0][lane] = dmin0; lidx[w][0][lane] = best0 + w * 128;
        lmin[w][1][lane] = dmin1; lidx[w][1][lane] = best1 + w * 128;
        __syncthreads();
        float d0c = lmin[0][0][lane]; int b0c = lidx[0][0][lane];
        float d1c = lmin[0][1][lane]; int b1c = lidx[0][1][lane];
#pragma unroll
        for (int ww = 1; ww < 4; ++ww) {
            const float dd0 = lmin[ww][0][lane]; const int ii0 = lidx[ww][0][lane];
            if (dd0 < d0c) { d0c = dd0; b0c = ii0; }
            const float dd1 = lmin[ww][1][lane]; const int ii1 = lidx[ww][1][lane];
            if (dd1 < d1c) { d1c = dd1; b1c = ii1; }
        }

        if (w < 2) {
            float lv = (w == 0) ? d0c : d1c;
#pragma unroll
            for (int off = 32; off; off >>= 1) lv += __shfl_down(lv, off, 64);
            if (lane == 0) atomicAdd(&loss_acc[s], lv);
        }
        if (w == 0)      idx_out[(size_t)t0 * 4 + s] = (float)b0c;
        else if (w == 1) idx_out[(size_t)t1 * 4 + s] = (float)b1c;

        const float4* c0 = (const float4*)(cb + ((size_t)s * 512 + b0c) * 64);
        const float4* c1 = (const float4*)(cb + ((size_t)s * 512 + b1c) * 64);
#pragma unroll
        for (int i = 0; i < 16; ++i) {
            float4 v = c0[i];
            r0[4 * i + 0] -= v.x; r0[4 * i + 1] -= v.y;
            r0[4 * i + 2] -= v.z; r0[4 * i + 3] -= v.w;
            float4 u = c1[i];
            r1[4 * i + 0] -= u.x; r1[4 * i + 1] -= u.y;
            r1[4 * i + 2] -= u.z; r1[4 * i + 3] -= u.w;
        }
    }

    if (w == 0) {
        const float4* zp = (const float4*)(z + (size_t)t0 * 64);
        const int n = t0 >> 12, pix = t0 & 4095;
        float* qp = q + (size_t)n * 64 * 4096 + pix;
#pragma unroll
        for (int i = 0; i < 16; ++i) {
            float4 v = zp[i];
            qp[(size_t)(4 * i + 0) * 4096] = v.x - r0[4 * i + 0];
            qp[(size_t)(4 * i + 1) * 4096] = v.y - r0[4 * i + 1];
            qp[(size_t)(4 * i + 2) * 4096] = v.z - r0[4 * i + 2];
            qp[(size_t)(4 * i + 3) * 4096] = v.w - r0[4 * i + 3];
        }
    } else if (w == 1) {
        const float4* zp = (const float4*)(z + (size_t)t1 * 64);
        const int n = t1 >> 12, pix = t1 & 4095;
        float* qp = q + (size_t)n * 64 * 4096 + pix;
#pragma unroll
        for (int i = 0; i < 16; ++i) {
            float4 v = zp[i];
            qp[(size_t)(4 * i + 0) * 4096] = v.x - r1[4 * i + 0];
            qp[(size_t)(4 * i + 1) * 4096] = v.y - r1[4 * i + 1];
            qp[(size_t)(4 * i + 2) * 4096] = v.z - r1[4 * i + 2];
            qp[(size_t)(4 * i + 3) * 4096] = v.w - r1[4 * i + 3];
        }
    }
}

__global__ void init_k(float* loss_acc) {
    if (threadIdx.x < 4) loss_acc[threadIdx.x] = 0.f;
}
__global__ void fin_k(const float* __restrict__ loss_acc, float* __restrict__ out_loss) {
    if (threadIdx.x < 4)
        out_loss[threadIdx.x] = loss_acc[threadIdx.x] * (0.25f / 4194304.f); // BETA/(N*D)
}

// ---------------------------------------------------------------------------
extern "C" void kernel_launch(void* const* d_in, const int* in_sizes, int n_in,
                              void* d_out, int out_size, void* d_ws, size_t ws_size,
                              hipStream_t stream)
{
    const float* x    = (const float*)d_in[0];
    const float* e1w  = (const float*)d_in[1];  const float* e1b = (const float*)d_in[2];
    const float* e2w  = (const float*)d_in[3];  const float* e2b = (const float*)d_in[4];
    const float* e3w  = (const float*)d_in[5];  const float* e3b = (const float*)d_in[6];
    const float* r1aw = (const float*)d_in[7];  const float* r1bw = (const float*)d_in[8];
    const float* r2aw = (const float*)d_in[9];  const float* r2bw = (const float*)d_in[10];
    const float* e4w  = (const float*)d_in[11]; const float* e4b = (const float*)d_in[12];
    const float* cbs  = (const float*)d_in[13];
    const float* d1w  = (const float*)d_in[14]; const float* d1b = (const float*)d_in[15];
    const float* dr1aw= (const float*)d_in[16]; const float* dr1bw = (const float*)d_in[17];
    const float* dr2aw= (const float*)d_in[18]; const float* dr2bw = (const float*)d_in[19];
    const float* dt1w = (const float*)d_in[20]; const float* dt1b = (const float*)d_in[21];
    const float* dt2w = (const float*)d_in[22]; const float* dt2b = (const float*)d_in[23];

    float* out = (float*)d_out;
    float* ws  = (float*)d_ws;

    float* BIG = ws;                    // 16.78M floats (e1 out / dt1 out)
    float* P2  = BIG;
    float* P3  = BIG + 8388608;
    float* P1  = ws + 16777216;
    float* Z   = ws + 25165824;
    float* Q   = ws + 29360128;
    float* LACC= ws + 33554432;         // 4 floats
    float* NRM = ws + 33554448;         // 2048 floats

    float* out_recons = out;                    // 16*4*256*256 = 4194304
    float* out_idx    = out + 4194304;          // 16*64*64*4   = 262144
    float* out_loss   = out + 4194304 + 262144; // 4

    init_k<<<1, 64, 0, stream>>>(LACC);
    norm_k<<<8, 256, 0, stream>>>(cbs, NRM);

    // ---- encoder ----
    conv_k<4, 64, 4, 2, 1, 256, 256, 128, 128, 4, 2, 2, true>
        <<<dim3(32, 4, 16), 256, 0, stream>>>(x, e1w, e1b, BIG);
    conv_k<64, 128, 4, 2, 1, 128, 128, 64, 64, 16, 2, 2, true>
        <<<dim3(8, 8, 16), 256, 0, stream>>>(BIG, e2w, e2b, P1);
    conv_k<128, 128, 3, 1, 1, 64, 64, 64, 64, 16, 4, 2, true>
        <<<dim3(4, 8, 16), 256, 0, stream>>>(P1, e3w, e3b, P2);
    conv_k<128, 128, 3, 1, 1, 64, 64, 64, 64, 16, 4, 1, false>
        <<<dim3(4, 8, 16), 256, 0, stream>>>(P2, r1aw, nullptr, P3);
    conv1x1_k<128, 128, 4, 0, false, false, true, false>
        <<<dim3(4, 8, 16), 256, 0, stream>>>(P3, r1bw, nullptr, P2, P1);
    conv_k<128, 128, 3, 1, 1, 64, 64, 64, 64, 16, 4, 1, false>
        <<<dim3(4, 8, 16), 256, 0, stream>>>(P1, r2aw, nullptr, P3);
    conv1x1_k<128, 128, 4, 0, false, false, true, false>
        <<<dim3(4, 8, 16), 256, 0, stream>>>(P3, r2bw, nullptr, P1, P2);
    conv1x1_k<128, 64, 2, 2, true, true, false, true>
        <<<dim3(8, 4, 16), 256, 0, stream>>>(P2, e4w, e4b, nullptr, Z);

    // ---- residual VQ ----
    rvq_k<<<512, 256, 0, stream>>>(Z, cbs, NRM, Q, out_idx, LACC);
    fin_k<<<1, 64, 0, stream>>>(LACC, out_loss);

    // ---- decoder ----
    conv_k<64, 128, 3, 1, 1, 64, 64, 64, 64, 16, 4, 2, true>
        <<<dim3(4, 8, 16), 256, 0, stream>>>(Q, d1w, d1b, P1);
    conv_k<128, 128, 3, 1, 1, 64, 64, 64, 64, 16, 4, 1, false>
        <<<dim3(4, 8, 16), 256, 0, stream>>>(P1, dr1aw, nullptr, P2);
    conv1x1_k<128, 128, 4, 0, false, false, true, false>
        <<<dim3(4, 8, 16), 256, 0, stream>>>(P2, dr1bw, nullptr, P1, P3);
    conv_k<128, 128, 3, 1, 1, 64, 64, 64, 64, 16, 4, 1, false>
        <<<dim3(4, 8, 16), 256, 0, stream>>>(P3, dr2aw, nullptr, P2);
    conv1x1_k<128, 128, 4, 0, false, false, true, false>
        <<<dim3(4, 8, 16), 256, 0, stream>>>(P2, dr2bw, nullptr, P3, P1);
    // dt1: OCT=8, 2 A-rows/thread -> grid (TBW=4 x 2 A-tiles = 8, 64/8 = 8, 16)
    convt_k<128, 64, 8, 64, 8, 2, true>
        <<<dim3(8, 8, 16), 256, 0, stream>>>(P1, dt1w, dt1b, BIG);
    // dt2: OCT=4 -> grid (TBW=8 x 4 A-tiles = 32, 1, 16)
    convt_k<64, 4, 4, 128, 16, 1, false>
        <<<dim3(32, 1, 16), 256, 0, stream>>>(BIG, dt2w, dt2b, out_recons);
}